// Round 7
// baseline (434.418 us; speedup 1.0000x reference)
//
#include <hip/hip_runtime.h>
#include <stdint.h>

// Problem constants (fixed by the reference)
constexpr int BB = 8;
constexpr int LL = 4096;
constexpr int DD = 128;
constexpr int KC = 1024;
constexpr int NN = BB * LL;          // 32768
constexpr int ZTOT = BB * DD * LL;   // 4194304

// Threefry variant: 1 = partitionable (JAX >= 0.4.36 default), 0 = original
#define THREEFRY_PARTITIONABLE 1

__device__ __forceinline__ uint32_t rotl32(uint32_t x, int r) {
  return (x << r) | (x >> (32 - r));
}

__device__ __forceinline__ void threefry2x32(uint32_t k0, uint32_t k1,
                                             uint32_t x0, uint32_t x1,
                                             uint32_t* o0, uint32_t* o1) {
  uint32_t ks0 = k0, ks1 = k1, ks2 = 0x1BD11BDAu ^ k0 ^ k1;
  x0 += ks0; x1 += ks1;
  // group 1: rot 13,15,26,6
  x0 += x1; x1 = rotl32(x1, 13); x1 ^= x0;
  x0 += x1; x1 = rotl32(x1, 15); x1 ^= x0;
  x0 += x1; x1 = rotl32(x1, 26); x1 ^= x0;
  x0 += x1; x1 = rotl32(x1, 6);  x1 ^= x0;
  x0 += ks1; x1 += ks2 + 1u;
  // group 2: rot 17,29,16,24
  x0 += x1; x1 = rotl32(x1, 17); x1 ^= x0;
  x0 += x1; x1 = rotl32(x1, 29); x1 ^= x0;
  x0 += x1; x1 = rotl32(x1, 16); x1 ^= x0;
  x0 += x1; x1 = rotl32(x1, 24); x1 ^= x0;
  x0 += ks2; x1 += ks0 + 2u;
  // group 3: rot 13,15,26,6
  x0 += x1; x1 = rotl32(x1, 13); x1 ^= x0;
  x0 += x1; x1 = rotl32(x1, 15); x1 ^= x0;
  x0 += x1; x1 = rotl32(x1, 26); x1 ^= x0;
  x0 += x1; x1 = rotl32(x1, 6);  x1 ^= x0;
  x0 += ks0; x1 += ks1 + 3u;
  // group 4: rot 17,29,16,24
  x0 += x1; x1 = rotl32(x1, 17); x1 ^= x0;
  x0 += x1; x1 = rotl32(x1, 29); x1 ^= x0;
  x0 += x1; x1 = rotl32(x1, 16); x1 ^= x0;
  x0 += x1; x1 = rotl32(x1, 24); x1 ^= x0;
  x0 += ks1; x1 += ks2 + 4u;
  // group 5: rot 13,15,26,6
  x0 += x1; x1 = rotl32(x1, 13); x1 ^= x0;
  x0 += x1; x1 = rotl32(x1, 15); x1 ^= x0;
  x0 += x1; x1 = rotl32(x1, 26); x1 ^= x0;
  x0 += x1; x1 = rotl32(x1, 6);  x1 ^= x0;
  x0 += ks2; x1 += ks0 + 5u;
  *o0 = x0; *o1 = x1;
}

// Kernel 0: e_sq per code, E transpose (ET[d][k]), zero accumulators
__global__ __launch_bounds__(128) void k_prep(const float* __restrict__ E,
                                              float* __restrict__ esq,
                                              float* __restrict__ wsum,
                                              float* __restrict__ counts,
                                              double* __restrict__ lacc,
                                              float* __restrict__ ET) {
  const int k = blockIdx.x;       // 1024 blocks (codes)
  const int d = threadIdx.x;      // 128 threads (dims)
  float v = E[k * DD + d];
  ET[(size_t)d * KC + k] = v;     // transposed codebook for k_dist staging
  __shared__ float r[128];
  r[d] = v * v;
  __syncthreads();
  for (int s = 64; s > 0; s >>= 1) {
    if (d < s) r[d] += r[d + s];
    __syncthreads();
  }
  if (d == 0) {
    esq[k] = r[0];
    counts[k] = 0.0f;
    if (k == 0) lacc[0] = 0.0;
  }
  wsum[k * DD + d] = 0.0f;
}

// Kernel 1: LDS-tiled distance GEMM + per-row argmin + counts + weighted sums.
// Block: 256 threads; 128 rows x (8 chunks of 128 codes); K=128 staged once.
// Per-thread 8 rows x 8 codes register tile (rows/codes split tx*4 / 64+tx*4
// so each ds_read_b128 lands lanes at 16B stride -> 2 lanes/bank, no conflict).
__global__ __launch_bounds__(256) void k_dist(const float* __restrict__ Z,
                                              const float* __restrict__ ET,
                                              const float* __restrict__ esq,
                                              int* __restrict__ idx_out,
                                              float* __restrict__ counts,
                                              float* __restrict__ wsum) {
  __shared__ float Zt[128][128];   // 64 KB  [k][row]
  __shared__ float Et[128][128];   // 64 KB  [k][code]
  __shared__ float cval[16][128];  // 8 KB
  __shared__ int   cidx[16][128];  // 8 KB
  __shared__ int   fidx[128];

  const int tid = threadIdx.x;
  const int tx = tid & 15;        // row group
  const int ty = tid >> 4;        // code group
  const int r0 = blockIdx.x * 128;
  const int b  = r0 >> 12;
  const int l0 = r0 & (LL - 1);

  // stage Z tile -> Zt[d][row]; 512B contiguous per d (coalesced)
  const float* zsrc = Z + (size_t)b * DD * LL + l0;
#pragma unroll
  for (int p = 0; p < 16; ++p) {
    int idx = p * 256 + tid;
    int d = idx >> 5;
    int g = idx & 31;
    float4 v = *(const float4*)(zsrc + (size_t)d * LL + g * 4);
    *(float4*)(&Zt[d][g * 4]) = v;
  }
  __syncthreads();

  // zsq for this thread's 8 rows (tx*4+{0..3}, 64+tx*4+{0..3})
  float zsq[8] = {0.f, 0.f, 0.f, 0.f, 0.f, 0.f, 0.f, 0.f};
#pragma unroll 4
  for (int k = 0; k < 128; ++k) {
    float4 a = *(const float4*)(&Zt[k][tx * 4]);
    float4 c = *(const float4*)(&Zt[k][64 + tx * 4]);
    zsq[0] = fmaf(a.x, a.x, zsq[0]);
    zsq[1] = fmaf(a.y, a.y, zsq[1]);
    zsq[2] = fmaf(a.z, a.z, zsq[2]);
    zsq[3] = fmaf(a.w, a.w, zsq[3]);
    zsq[4] = fmaf(c.x, c.x, zsq[4]);
    zsq[5] = fmaf(c.y, c.y, zsq[5]);
    zsq[6] = fmaf(c.z, c.z, zsq[6]);
    zsq[7] = fmaf(c.w, c.w, zsq[7]);
  }

  float best[8];
  int bidx[8];
#pragma unroll
  for (int i = 0; i < 8; ++i) { best[i] = 3.4e38f; bidx[i] = 0; }

  for (int ch = 0; ch < 8; ++ch) {
    const int cbase = ch * 128;
    __syncthreads();   // previous chunk's Et reads complete
    // stage E chunk from ET -> Et[d][code] (coalesced)
#pragma unroll
    for (int p = 0; p < 16; ++p) {
      int idx = p * 256 + tid;
      int d = idx >> 5;
      int g = idx & 31;
      float4 v = *(const float4*)(ET + (size_t)d * KC + cbase + g * 4);
      *(float4*)(&Et[d][g * 4]) = v;
    }
    __syncthreads();

    float acc[8][8];
#pragma unroll
    for (int i = 0; i < 8; ++i)
#pragma unroll
      for (int j = 0; j < 8; ++j) acc[i][j] = 0.f;

#pragma unroll 4
    for (int k = 0; k < 128; ++k) {
      float4 z1 = *(const float4*)(&Zt[k][tx * 4]);
      float4 z2 = *(const float4*)(&Zt[k][64 + tx * 4]);
      float4 e1 = *(const float4*)(&Et[k][ty * 4]);
      float4 e2 = *(const float4*)(&Et[k][64 + ty * 4]);
      float zr[8] = {z1.x, z1.y, z1.z, z1.w, z2.x, z2.y, z2.z, z2.w};
      float ec[8] = {e1.x, e1.y, e1.z, e1.w, e2.x, e2.y, e2.z, e2.w};
#pragma unroll
      for (int i = 0; i < 8; ++i)
#pragma unroll
        for (int j = 0; j < 8; ++j)
          acc[i][j] = fmaf(zr[i], ec[j], acc[i][j]);
    }

    // finalize keys; ascending c within thread + strict < => first-index tie-break
#pragma unroll
    for (int j = 0; j < 8; ++j) {
      int c = cbase + ((j < 4) ? (ty * 4 + j) : (64 + ty * 4 + (j - 4)));
      float eq = esq[c];
#pragma unroll
      for (int i = 0; i < 8; ++i) {
        float key = (zsq[i] + eq) - 2.0f * acc[i][j];   // reference expr tree
        if (key < best[i]) { best[i] = key; bidx[i] = c; }
      }
    }
  }

  // per-thread candidates -> LDS
#pragma unroll
  for (int i = 0; i < 8; ++i) {
    int col = (i < 4) ? (tx * 4 + i) : (64 + tx * 4 + (i - 4));
    cval[ty][col] = best[i];
    cidx[ty][col] = bidx[i];
  }
  __syncthreads();

  // combine 16 candidates per row, lexicographic (val, idx)
  if (tid < 128) {
    float fb = cval[0][tid];
    int fi = cidx[0][tid];
#pragma unroll
    for (int j = 1; j < 16; ++j) {
      float v = cval[j][tid];
      int ii = cidx[j][tid];
      if (v < fb || (v == fb && ii < fi)) { fb = v; fi = ii; }
    }
    idx_out[r0 + tid] = fi;
    atomicAdd(&counts[fi], 1.0f);   // integer-valued fp32: exact
    fidx[tid] = fi;
  }
  __syncthreads();

  // scatter weighted sums: 2 threads per row, 64 dims each
  {
    int r = tid >> 1;
    int h = tid & 1;
    int fi = fidx[r];
    float* wrow = wsum + (size_t)fi * DD + h * 64;
#pragma unroll
    for (int dd = 0; dd < 64; ++dd) {
      atomicAdd(&wrow[dd], Zt[h * 64 + dd][r]);
    }
  }
}

// Kernel 2: cluster-size EMA, dead detection, threefry restart indices, smoothing
__global__ __launch_bounds__(1024) void k_cluster(const float* __restrict__ counts,
                                                  const float* __restrict__ cs_in,
                                                  float* __restrict__ smooth,
                                                  int* __restrict__ ridx,
                                                  int* __restrict__ deadf) {
  const int k = threadIdx.x;   // 1024 threads, 1 block
  float c = counts[k];
  float t1 = 0.99f * cs_in[k];
  float t2 = 0.01f * c;        // f32(1.0 - 0.99) == f32(0.01)
  float nc = t1 + t2;
  bool dead = nc < 0.5f;

  uint32_t bits;
#if THREEFRY_PARTITIONABLE
  {
    uint32_t o0, o1;
    threefry2x32(0u, 42u, 0u, (uint32_t)k, &o0, &o1);  // counter = (hi=0, lo=k)
    bits = o0 ^ o1;
  }
#else
  {
    uint32_t o0, o1;
    if (k < 512) { threefry2x32(0u, 42u, (uint32_t)k, (uint32_t)(k + 512), &o0, &o1); bits = o0; }
    else         { threefry2x32(0u, 42u, (uint32_t)(k - 512), (uint32_t)k, &o0, &o1); bits = o1; }
  }
#endif
  int r = (int)(bits & 0x7FFFu);   // span=32768 (pow2): randint == bits mod 2^15

  float rep = dead ? 0.5f : nc;

  __shared__ float red[1024];
  red[k] = rep;
  __syncthreads();
  for (int s = 512; s > 0; s >>= 1) {
    if (k < s) red[k] += red[k + s];
    __syncthreads();
  }
  float n = red[0];

  float sm = ((rep + 1e-5f) / (n + 0.01024f)) * n;   // (nc+EPS)/(n+K*EPS)*n
  smooth[k] = sm;
  ridx[k] = r;
  deadf[k] = dead ? 1 : 0;
}

// Kernel 3: new embedding = (EMA avg or restart vec) / smoothed
__global__ __launch_bounds__(256) void k_emb(const float* __restrict__ wsum,
                                             const float* __restrict__ avg_in,
                                             const float* __restrict__ Z,
                                             const float* __restrict__ smooth,
                                             const int* __restrict__ ridx,
                                             const int* __restrict__ deadf,
                                             float* __restrict__ nemb) {
  int kd = blockIdx.x * 256 + threadIdx.x;   // < 131072
  int k = kd >> 7;
  int d = kd & (DD - 1);
  float t1 = 0.99f * avg_in[kd];
  float t2 = 0.01f * wsum[kd];
  float na = t1 + t2;
  if (deadf[k]) {
    int r = ridx[k];
    float zv = Z[((size_t)(r >> 12) * DD + d) * LL + (r & (LL - 1))];
    na = zv * 0.5f;   // rvec * RESTART_THRESHOLD
  }
  nemb[kd] = na / smooth[k];
}

// Kernel 4: gather z_q, write z_q_st + indices_map, accumulate squared-error
__global__ __launch_bounds__(256) void k_out(const float* __restrict__ Z,
                                             const float* __restrict__ nemb,
                                             const int* __restrict__ idxs,
                                             float* __restrict__ out,
                                             double* __restrict__ lacc) {
  int t = blockIdx.x * 256 + threadIdx.x;   // 1048576 threads, 4 l-elems each
  int l4 = t & (LL / 4 - 1);                // 1024
  int d = (t >> 10) & (DD - 1);
  int b = t >> 17;
  size_t zoff = ((size_t)(b * DD + d)) * LL + (size_t)l4 * 4;
  const float4 ze = *(const float4*)(Z + zoff);
  int n0 = b * LL + l4 * 4;
  int i0 = idxs[n0 + 0], i1 = idxs[n0 + 1], i2 = idxs[n0 + 2], i3 = idxs[n0 + 3];
  float q0 = nemb[(size_t)i0 * DD + d];
  float q1 = nemb[(size_t)i1 * DD + d];
  float q2 = nemb[(size_t)i2 * DD + d];
  float q3 = nemb[(size_t)i3 * DD + d];
  float4 o;
  o.x = ze.x + (q0 - ze.x);   // z_q_st = z_e + (z_q - z_e), reference expr tree
  o.y = ze.y + (q1 - ze.y);
  o.z = ze.z + (q2 - ze.z);
  o.w = ze.w + (q3 - ze.w);
  *(float4*)(out + zoff) = o;
  if (d == 0) {
    float* oi = out + (size_t)ZTOT;
    oi[n0 + 0] = (float)i0;
    oi[n0 + 1] = (float)i1;
    oi[n0 + 2] = (float)i2;
    oi[n0 + 3] = (float)i3;
  }
  float d0 = ze.x - q0, d1 = ze.y - q1, d2 = ze.z - q2, d3 = ze.w - q3;
  float s = d0 * d0 + d1 * d1 + d2 * d2 + d3 * d3;
  for (int off = 32; off > 0; off >>= 1) s += __shfl_down(s, off, 64);
  __shared__ float wsums[4];
  if ((threadIdx.x & 63) == 0) wsums[threadIdx.x >> 6] = s;
  __syncthreads();
  if (threadIdx.x == 0) {
    float tot = (wsums[0] + wsums[1]) + (wsums[2] + wsums[3]);
    atomicAdd(lacc, (double)tot);
  }
}

// Kernel 5: final loss scalars
__global__ void k_fin(const double* __restrict__ lacc, float* __restrict__ out) {
  double S = lacc[0];
  float cb = (float)(S / (double)ZTOT);   // codebook_loss == commitment_loss numerically
  float bc = 0.25f * cb;
  float vq = cb + bc;
  float* o = out + (size_t)ZTOT + NN;
  o[0] = vq;
  o[1] = cb;
  o[2] = bc;
}

extern "C" void kernel_launch(void* const* d_in, const int* in_sizes, int n_in,
                              void* d_out, int out_size, void* d_ws, size_t ws_size,
                              hipStream_t stream) {
  const float* Z  = (const float*)d_in[0];   // z_e        (8,128,4096)
  const float* E  = (const float*)d_in[1];   // embedding  (1024,128)
  const float* CS = (const float*)d_in[2];   // cluster_size (1024,)
  const float* EA = (const float*)d_in[3];   // embedding_avg (1024,128)
  float* out = (float*)d_out;
  float* ws = (float*)d_ws;

  float* counts = ws;                        // 1024
  float* esq    = ws + 1024;                 // 1024
  float* smooth = ws + 2048;                 // 1024
  int*   ridx   = (int*)(ws + 3072);         // 1024
  int*   deadf  = (int*)(ws + 4096);         // 1024
  float* wsum   = ws + 8192;                 // 131072
  float* nemb   = ws + 8192 + 131072;        // 131072 floats (512 KB)
  int*   idxs   = (int*)(ws + 270336);       // 32768
  double* lacc  = (double*)(ws + 303104);    // byte offset 1212416, 8B aligned

  // ET (transposed codebook, 512 KB) reuses the nemb slot: it is consumed by
  // k_dist and only afterwards does k_emb overwrite nemb (stream-ordered).
  float* ET = nemb;

  k_prep<<<KC, DD, 0, stream>>>(E, esq, wsum, counts, lacc, ET);
  k_dist<<<NN / 128, 256, 0, stream>>>(Z, ET, esq, idxs, counts, wsum);
  k_cluster<<<1, KC, 0, stream>>>(counts, CS, smooth, ridx, deadf);
  k_emb<<<(KC * DD) / 256, 256, 0, stream>>>(wsum, EA, Z, smooth, ridx, deadf, nemb);
  k_out<<<(ZTOT / 4) / 256, 256, 0, stream>>>(Z, nemb, idxs, out, lacc);
  k_fin<<<1, 1, 0, stream>>>(lacc, out);
}

// Round 8
// 423.941 us; speedup vs baseline: 1.0247x; 1.0247x over previous
//
#include <hip/hip_runtime.h>
#include <stdint.h>

// Problem constants (fixed by the reference)
constexpr int BB = 8;
constexpr int LL = 4096;
constexpr int DD = 128;
constexpr int KC = 1024;
constexpr int NN = BB * LL;          // 32768
constexpr int ZTOT = BB * DD * LL;   // 4194304

#define THREEFRY_PARTITIONABLE 1

typedef float f32x16 __attribute__((ext_vector_type(16)));
typedef short s16x8 __attribute__((ext_vector_type(8)));

union F4S8 { float4 f; s16x8 s; };

__device__ __forceinline__ ushort f2bf(float x) {   // RNE float->bf16
  uint32_t u = __float_as_uint(x);
  uint32_t r = u + 0x7FFFu + ((u >> 16) & 1u);
  return (ushort)(r >> 16);
}
__device__ __forceinline__ float bf2f(ushort h) {
  return __uint_as_float(((uint32_t)h) << 16);
}

__device__ __forceinline__ uint32_t rotl32(uint32_t x, int r) {
  return (x << r) | (x >> (32 - r));
}

__device__ __forceinline__ void threefry2x32(uint32_t k0, uint32_t k1,
                                             uint32_t x0, uint32_t x1,
                                             uint32_t* o0, uint32_t* o1) {
  uint32_t ks0 = k0, ks1 = k1, ks2 = 0x1BD11BDAu ^ k0 ^ k1;
  x0 += ks0; x1 += ks1;
  x0 += x1; x1 = rotl32(x1, 13); x1 ^= x0;
  x0 += x1; x1 = rotl32(x1, 15); x1 ^= x0;
  x0 += x1; x1 = rotl32(x1, 26); x1 ^= x0;
  x0 += x1; x1 = rotl32(x1, 6);  x1 ^= x0;
  x0 += ks1; x1 += ks2 + 1u;
  x0 += x1; x1 = rotl32(x1, 17); x1 ^= x0;
  x0 += x1; x1 = rotl32(x1, 29); x1 ^= x0;
  x0 += x1; x1 = rotl32(x1, 16); x1 ^= x0;
  x0 += x1; x1 = rotl32(x1, 24); x1 ^= x0;
  x0 += ks2; x1 += ks0 + 2u;
  x0 += x1; x1 = rotl32(x1, 13); x1 ^= x0;
  x0 += x1; x1 = rotl32(x1, 15); x1 ^= x0;
  x0 += x1; x1 = rotl32(x1, 26); x1 ^= x0;
  x0 += x1; x1 = rotl32(x1, 6);  x1 ^= x0;
  x0 += ks0; x1 += ks1 + 3u;
  x0 += x1; x1 = rotl32(x1, 17); x1 ^= x0;
  x0 += x1; x1 = rotl32(x1, 29); x1 ^= x0;
  x0 += x1; x1 = rotl32(x1, 16); x1 ^= x0;
  x0 += x1; x1 = rotl32(x1, 24); x1 ^= x0;
  x0 += ks1; x1 += ks2 + 4u;
  x0 += x1; x1 = rotl32(x1, 13); x1 ^= x0;
  x0 += x1; x1 = rotl32(x1, 15); x1 ^= x0;
  x0 += x1; x1 = rotl32(x1, 26); x1 ^= x0;
  x0 += x1; x1 = rotl32(x1, 6);  x1 ^= x0;
  x0 += ks2; x1 += ks0 + 5u;
  *o0 = x0; *o1 = x1;
}

// Kernel 0: e_sq per code, bf16-split E fragments (MFMA A-layout linear), zero accum.
// Frag layout: slot = ((k>>5)*8 + ks)*64 + (k&31) + 32*h ; 8 bf16 = dims ks*16+h*8+j.
__global__ __launch_bounds__(128) void k_prep(const float* __restrict__ E,
                                              float* __restrict__ esq,
                                              float* __restrict__ wsum,
                                              float* __restrict__ counts,
                                              double* __restrict__ lacc,
                                              ushort* __restrict__ E0f,
                                              ushort* __restrict__ E1f) {
  const int k = blockIdx.x;       // code
  const int d = threadIdx.x;      // dim
  float v = E[k * DD + d];
  __shared__ float r[128];
  __shared__ ushort sh0[128], sh1[128];
  ushort h0 = f2bf(v);
  float v0 = bf2f(h0);
  ushort h1 = f2bf(v - v0);
  sh0[d] = h0; sh1[d] = h1;
  r[d] = v * v;
  __syncthreads();
  for (int s = 64; s > 0; s >>= 1) {
    if (d < s) r[d] += r[d + s];
    __syncthreads();
  }
  if (d == 0) {
    esq[k] = r[0];
    counts[k] = 0.0f;
    if (k == 0) lacc[0] = 0.0;
  }
  wsum[k * DD + d] = 0.0f;
  if (d < 32) {
    const ushort* src = (d < 16) ? sh0 : sh1;
    ushort* dst = (d < 16) ? E0f : E1f;
    int p = d & 15, h = p & 1, ks = p >> 1;
    int slot = ((k >> 5) * 8 + ks) * 64 + (k & 31) + 32 * h;
    int off = ks * 16 + h * 8;
    uint32_t w0 = (uint32_t)src[off + 0] | ((uint32_t)src[off + 1] << 16);
    uint32_t w1 = (uint32_t)src[off + 2] | ((uint32_t)src[off + 3] << 16);
    uint32_t w2 = (uint32_t)src[off + 4] | ((uint32_t)src[off + 5] << 16);
    uint32_t w3 = (uint32_t)src[off + 6] | ((uint32_t)src[off + 7] << 16);
    uint4 val; val.x = w0; val.y = w1; val.z = w2; val.w = w3;
    *(uint4*)(dst + (size_t)slot * 8) = val;
  }
}

// Kernel 1: MFMA distance GEMM (bf16x2-split, 3 passes) + lane-local argmin +
// selective exact refine + counts + weighted sums.
// Block: 256 thr = 4 waves; wave w owns 32 rows; A=E (codes), B=Z (rows).
__global__ __launch_bounds__(256) void k_dist(const float* __restrict__ Z,
                                              const float* __restrict__ E,
                                              const ushort* __restrict__ E0f,
                                              const ushort* __restrict__ E1f,
                                              const float* __restrict__ esq,
                                              int* __restrict__ idx_out,
                                              float* __restrict__ counts,
                                              float* __restrict__ wsum) {
  __shared__ float Zt[128][128];   // [dim][row] fp32, 64 KB, lives whole kernel
  __shared__ float esh[1024];      // 4 KB
  __shared__ int fidx[128];

  const int tid = threadIdx.x;
  const int w = tid >> 6;
  const int lane = tid & 63;
  const int hi = lane >> 5;
  const int rr = lane & 31;
  const int rloc = w * 32 + rr;
  const int r0 = blockIdx.x * 128;
  const int b = r0 >> 12;
  const int l0 = r0 & (LL - 1);

  // stage Z tile (coalesced: 512B contiguous per dim)
  const float* zsrc = Z + (size_t)b * DD * LL + l0;
#pragma unroll
  for (int p = 0; p < 16; ++p) {
    int idx = p * 256 + tid;
    int d = idx >> 5;
    int g = idx & 31;
    float4 v = *(const float4*)(zsrc + (size_t)d * LL + g * 4);
    *(float4*)(&Zt[d][g * 4]) = v;
  }
  {  // stage esq
    float4 e4 = *(const float4*)(esq + tid * 4);
    *(float4*)(&esh[tid * 4]) = e4;
  }
  __syncthreads();

  // build B-frags (z bf16 splits): lane holds row rloc, dims ks*16+hi*8+j
  s16x8 B0[8], B1[8];
#pragma unroll
  for (int ks = 0; ks < 8; ++ks) {
    s16x8 b0, b1;
#pragma unroll
    for (int j = 0; j < 8; ++j) {
      float z = Zt[ks * 16 + hi * 8 + j][rloc];
      ushort h0 = f2bf(z);
      float z0f = bf2f(h0);
      ushort h1 = f2bf(z - z0f);
      b0[j] = (short)h0;
      b1[j] = (short)h1;
    }
    B0[ks] = b0; B1[ks] = b1;
  }
  // zsq (serial fma, matches prior passing kernels)
  float zsq = 0.0f;
  if (hi == 0) {
#pragma unroll 4
    for (int d = 0; d < 128; ++d) {
      float z = Zt[d][rloc];
      zsq = fmaf(z, z, zsq);
    }
  }
  zsq = __shfl(zsq, rr, 64);

  // main loop: 32 code-subtiles of 32
  float b1v = 3.4e38f, b2v = 3.4e38f;
  int b1i = 0, b2i = 0;
  const float4* e0p = (const float4*)E0f;
  const float4* e1p = (const float4*)E1f;

  for (int s = 0; s < 32; ++s) {
    f32x16 acc;
#pragma unroll
    for (int i = 0; i < 16; ++i) acc[i] = 0.0f;
    const int base = s * 8 * 64 + lane;
#pragma unroll
    for (int ks = 0; ks < 8; ++ks) {
      F4S8 ua, ub;
      ua.f = e0p[base + ks * 64];
      ub.f = e1p[base + ks * 64];
      acc = __builtin_amdgcn_mfma_f32_32x32x16_bf16(ua.s, B0[ks], acc, 0, 0, 0);
      acc = __builtin_amdgcn_mfma_f32_32x32x16_bf16(ua.s, B1[ks], acc, 0, 0, 0);
      acc = __builtin_amdgcn_mfma_f32_32x32x16_bf16(ub.s, B0[ks], acc, 0, 0, 0);
    }
    // finalize: lane-local codes, strictly increasing -> first-index tie-break
#pragma unroll
    for (int reg = 0; reg < 16; ++reg) {
      int cl = (reg & 3) + 8 * (reg >> 2) + 4 * hi;
      int c = s * 32 + cl;
      float rv = fmaf(-2.0f, acc[reg], esh[c]);   // zsq-free ranking key
      if (rv < b1v) { b2v = b1v; b2i = b1i; b1v = rv; b1i = c; }
      else if (rv < b2v) { b2v = rv; b2i = c; }
    }
  }

  // merge the two half-lanes (codes interleave -> lexicographic (val, idx))
  float ov1 = __shfl_xor(b1v, 32, 64); int oi1 = __shfl_xor(b1i, 32, 64);
  float ov2 = __shfl_xor(b2v, 32, 64); int oi2 = __shfl_xor(b2i, 32, 64);
  if (ov1 < b1v || (ov1 == b1v && oi1 < b1i)) { b2v = b1v; b2i = b1i; b1v = ov1; b1i = oi1; }
  else if (ov1 < b2v || (ov1 == b2v && oi1 < b2i)) { b2v = ov1; b2i = oi1; }
  if (ov2 < b2v || (ov2 == b2v && oi2 < b2i)) { b2v = ov2; b2i = oi2; }

  // selective exact refine (reference fp32 expression tree), ~1% of rows
  int fi = b1i;
  if (b2v - b1v <= 4e-5f) {
    float dot1 = 0.0f, dot2 = 0.0f;
    const float* e1r = E + (size_t)b1i * DD;
    const float* e2r = E + (size_t)b2i * DD;
    for (int d = 0; d < 128; ++d) {
      float z = Zt[d][rloc];
      dot1 = fmaf(z, e1r[d], dot1);
      dot2 = fmaf(z, e2r[d], dot2);
    }
    float k1 = (zsq + esh[b1i]) - 2.0f * dot1;
    float k2 = (zsq + esh[b2i]) - 2.0f * dot2;
    if (k2 < k1 || (k2 == k1 && b2i < b1i)) fi = b2i;
  }

  if (hi == 0) {
    int grow = r0 + rloc;
    idx_out[grow] = fi;
    atomicAdd(&counts[fi], 1.0f);   // integer-valued fp32: exact
    fidx[rloc] = fi;
  }
  __syncthreads();

  // scatter weighted sums: 2 threads per row, 64 dims each
  {
    int r = tid >> 1;
    int h = tid & 1;
    int f = fidx[r];
    float* wrow = wsum + (size_t)f * DD + h * 64;
#pragma unroll
    for (int dd = 0; dd < 64; ++dd) {
      atomicAdd(&wrow[dd], Zt[h * 64 + dd][r]);
    }
  }
}

// Kernel 2: cluster-size EMA, dead detection, threefry restart indices, smoothing
__global__ __launch_bounds__(1024) void k_cluster(const float* __restrict__ counts,
                                                  const float* __restrict__ cs_in,
                                                  float* __restrict__ smooth,
                                                  int* __restrict__ ridx,
                                                  int* __restrict__ deadf) {
  const int k = threadIdx.x;
  float c = counts[k];
  float t1 = 0.99f * cs_in[k];
  float t2 = 0.01f * c;
  float nc = t1 + t2;
  bool dead = nc < 0.5f;

  uint32_t bits;
#if THREEFRY_PARTITIONABLE
  {
    uint32_t o0, o1;
    threefry2x32(0u, 42u, 0u, (uint32_t)k, &o0, &o1);
    bits = o0 ^ o1;
  }
#else
  {
    uint32_t o0, o1;
    if (k < 512) { threefry2x32(0u, 42u, (uint32_t)k, (uint32_t)(k + 512), &o0, &o1); bits = o0; }
    else         { threefry2x32(0u, 42u, (uint32_t)(k - 512), (uint32_t)k, &o0, &o1); bits = o1; }
  }
#endif
  int r = (int)(bits & 0x7FFFu);

  float rep = dead ? 0.5f : nc;

  __shared__ float red[1024];
  red[k] = rep;
  __syncthreads();
  for (int s = 512; s > 0; s >>= 1) {
    if (k < s) red[k] += red[k + s];
    __syncthreads();
  }
  float n = red[0];

  float sm = ((rep + 1e-5f) / (n + 0.01024f)) * n;
  smooth[k] = sm;
  ridx[k] = r;
  deadf[k] = dead ? 1 : 0;
}

// Kernel 3: new embedding = (EMA avg or restart vec) / smoothed
__global__ __launch_bounds__(256) void k_emb(const float* __restrict__ wsum,
                                             const float* __restrict__ avg_in,
                                             const float* __restrict__ Z,
                                             const float* __restrict__ smooth,
                                             const int* __restrict__ ridx,
                                             const int* __restrict__ deadf,
                                             float* __restrict__ nemb) {
  int kd = blockIdx.x * 256 + threadIdx.x;
  int k = kd >> 7;
  int d = kd & (DD - 1);
  float t1 = 0.99f * avg_in[kd];
  float t2 = 0.01f * wsum[kd];
  float na = t1 + t2;
  if (deadf[k]) {
    int r = ridx[k];
    float zv = Z[((size_t)(r >> 12) * DD + d) * LL + (r & (LL - 1))];
    na = zv * 0.5f;
  }
  nemb[kd] = na / smooth[k];
}

// Kernel 4: gather z_q, write z_q_st + indices_map, accumulate squared-error
__global__ __launch_bounds__(256) void k_out(const float* __restrict__ Z,
                                             const float* __restrict__ nemb,
                                             const int* __restrict__ idxs,
                                             float* __restrict__ out,
                                             double* __restrict__ lacc) {
  int t = blockIdx.x * 256 + threadIdx.x;
  int l4 = t & (LL / 4 - 1);
  int d = (t >> 10) & (DD - 1);
  int b = t >> 17;
  size_t zoff = ((size_t)(b * DD + d)) * LL + (size_t)l4 * 4;
  const float4 ze = *(const float4*)(Z + zoff);
  int n0 = b * LL + l4 * 4;
  int i0 = idxs[n0 + 0], i1 = idxs[n0 + 1], i2 = idxs[n0 + 2], i3 = idxs[n0 + 3];
  float q0 = nemb[(size_t)i0 * DD + d];
  float q1 = nemb[(size_t)i1 * DD + d];
  float q2 = nemb[(size_t)i2 * DD + d];
  float q3 = nemb[(size_t)i3 * DD + d];
  float4 o;
  o.x = ze.x + (q0 - ze.x);
  o.y = ze.y + (q1 - ze.y);
  o.z = ze.z + (q2 - ze.z);
  o.w = ze.w + (q3 - ze.w);
  *(float4*)(out + zoff) = o;
  if (d == 0) {
    float* oi = out + (size_t)ZTOT;
    oi[n0 + 0] = (float)i0;
    oi[n0 + 1] = (float)i1;
    oi[n0 + 2] = (float)i2;
    oi[n0 + 3] = (float)i3;
  }
  float d0 = ze.x - q0, d1 = ze.y - q1, d2 = ze.z - q2, d3 = ze.w - q3;
  float s = d0 * d0 + d1 * d1 + d2 * d2 + d3 * d3;
  for (int off = 32; off > 0; off >>= 1) s += __shfl_down(s, off, 64);
  __shared__ float wsums[4];
  if ((threadIdx.x & 63) == 0) wsums[threadIdx.x >> 6] = s;
  __syncthreads();
  if (threadIdx.x == 0) {
    float tot = (wsums[0] + wsums[1]) + (wsums[2] + wsums[3]);
    atomicAdd(lacc, (double)tot);
  }
}

// Kernel 5: final loss scalars
__global__ void k_fin(const double* __restrict__ lacc, float* __restrict__ out) {
  double S = lacc[0];
  float cb = (float)(S / (double)ZTOT);
  float bc = 0.25f * cb;
  float vq = cb + bc;
  float* o = out + (size_t)ZTOT + NN;
  o[0] = vq;
  o[1] = cb;
  o[2] = bc;
}

extern "C" void kernel_launch(void* const* d_in, const int* in_sizes, int n_in,
                              void* d_out, int out_size, void* d_ws, size_t ws_size,
                              hipStream_t stream) {
  const float* Z  = (const float*)d_in[0];   // z_e        (8,128,4096)
  const float* E  = (const float*)d_in[1];   // embedding  (1024,128)
  const float* CS = (const float*)d_in[2];   // cluster_size (1024,)
  const float* EA = (const float*)d_in[3];   // embedding_avg (1024,128)
  float* out = (float*)d_out;
  float* ws = (float*)d_ws;

  float* counts = ws;                        // 1024
  float* esq    = ws + 1024;                 // 1024
  float* smooth = ws + 2048;                 // 1024
  int*   ridx   = (int*)(ws + 3072);         // 1024
  int*   deadf  = (int*)(ws + 4096);         // 1024
  float* wsum   = ws + 8192;                 // 131072
  float* nemb   = ws + 8192 + 131072;        // 131072 floats (512 KB)
  int*   idxs   = (int*)(ws + 270336);       // 32768
  double* lacc  = (double*)(ws + 303104);    // 8B aligned

  // bf16-split E fragment buffers (256 KB each) reuse the nemb slot:
  // consumed by k_dist, overwritten later by k_emb (stream-ordered).
  ushort* E0f = (ushort*)nemb;               // 65536 floats worth
  ushort* E1f = (ushort*)(nemb + 65536);

  k_prep<<<KC, DD, 0, stream>>>(E, esq, wsum, counts, lacc, E0f, E1f);
  k_dist<<<NN / 128, 256, 0, stream>>>(Z, E, E0f, E1f, esq, idxs, counts, wsum);
  k_cluster<<<1, KC, 0, stream>>>(counts, CS, smooth, ridx, deadf);
  k_emb<<<(KC * DD) / 256, 256, 0, stream>>>(wsum, EA, Z, smooth, ridx, deadf, nemb);
  k_out<<<(ZTOT / 4) / 256, 256, 0, stream>>>(Z, nemb, idxs, out, lacc);
  k_fin<<<1, 1, 0, stream>>>(lacc, out);
}

// Round 9
// 232.619 us; speedup vs baseline: 1.8675x; 1.8225x over previous
//
#include <hip/hip_runtime.h>
#include <stdint.h>

// Problem constants (fixed by the reference)
constexpr int BB = 8;
constexpr int LL = 4096;
constexpr int DD = 128;
constexpr int KC = 1024;
constexpr int NN = BB * LL;          // 32768
constexpr int ZTOT = BB * DD * LL;   // 4194304

#define THREEFRY_PARTITIONABLE 1

typedef float f32x16 __attribute__((ext_vector_type(16)));
typedef short s16x8 __attribute__((ext_vector_type(8)));

union F4S8 { float4 f; s16x8 s; };

__device__ __forceinline__ ushort f2bf(float x) {   // RNE float->bf16
  uint32_t u = __float_as_uint(x);
  uint32_t r = u + 0x7FFFu + ((u >> 16) & 1u);
  return (ushort)(r >> 16);
}
__device__ __forceinline__ float bf2f(ushort h) {
  return __uint_as_float(((uint32_t)h) << 16);
}

__device__ __forceinline__ uint32_t rotl32(uint32_t x, int r) {
  return (x << r) | (x >> (32 - r));
}

__device__ __forceinline__ void threefry2x32(uint32_t k0, uint32_t k1,
                                             uint32_t x0, uint32_t x1,
                                             uint32_t* o0, uint32_t* o1) {
  uint32_t ks0 = k0, ks1 = k1, ks2 = 0x1BD11BDAu ^ k0 ^ k1;
  x0 += ks0; x1 += ks1;
  x0 += x1; x1 = rotl32(x1, 13); x1 ^= x0;
  x0 += x1; x1 = rotl32(x1, 15); x1 ^= x0;
  x0 += x1; x1 = rotl32(x1, 26); x1 ^= x0;
  x0 += x1; x1 = rotl32(x1, 6);  x1 ^= x0;
  x0 += ks1; x1 += ks2 + 1u;
  x0 += x1; x1 = rotl32(x1, 17); x1 ^= x0;
  x0 += x1; x1 = rotl32(x1, 29); x1 ^= x0;
  x0 += x1; x1 = rotl32(x1, 16); x1 ^= x0;
  x0 += x1; x1 = rotl32(x1, 24); x1 ^= x0;
  x0 += ks2; x1 += ks0 + 2u;
  x0 += x1; x1 = rotl32(x1, 13); x1 ^= x0;
  x0 += x1; x1 = rotl32(x1, 15); x1 ^= x0;
  x0 += x1; x1 = rotl32(x1, 26); x1 ^= x0;
  x0 += x1; x1 = rotl32(x1, 6);  x1 ^= x0;
  x0 += ks0; x1 += ks1 + 3u;
  x0 += x1; x1 = rotl32(x1, 17); x1 ^= x0;
  x0 += x1; x1 = rotl32(x1, 29); x1 ^= x0;
  x0 += x1; x1 = rotl32(x1, 16); x1 ^= x0;
  x0 += x1; x1 = rotl32(x1, 24); x1 ^= x0;
  x0 += ks1; x1 += ks2 + 4u;
  x0 += x1; x1 = rotl32(x1, 13); x1 ^= x0;
  x0 += x1; x1 = rotl32(x1, 15); x1 ^= x0;
  x0 += x1; x1 = rotl32(x1, 26); x1 ^= x0;
  x0 += x1; x1 = rotl32(x1, 6);  x1 ^= x0;
  x0 += ks2; x1 += ks0 + 5u;
  *o0 = x0; *o1 = x1;
}

// Kernel 0: e_sq per code, bf16-split E fragments (MFMA A-layout linear), lacc init.
// Frag layout: slot = ((k>>5)*8 + ks)*64 + (k&31) + 32*h ; 8 bf16 = dims ks*16+h*8+j.
__global__ __launch_bounds__(128) void k_prep(const float* __restrict__ E,
                                              float* __restrict__ esq,
                                              double* __restrict__ lacc,
                                              ushort* __restrict__ E0f,
                                              ushort* __restrict__ E1f) {
  const int k = blockIdx.x;       // code
  const int d = threadIdx.x;      // dim
  float v = E[k * DD + d];
  __shared__ float r[128];
  __shared__ ushort sh0[128], sh1[128];
  ushort h0 = f2bf(v);
  float v0 = bf2f(h0);
  ushort h1 = f2bf(v - v0);
  sh0[d] = h0; sh1[d] = h1;
  r[d] = v * v;
  __syncthreads();
  for (int s = 64; s > 0; s >>= 1) {
    if (d < s) r[d] += r[d + s];
    __syncthreads();
  }
  if (d == 0) {
    esq[k] = r[0];
    if (k == 0) lacc[0] = 0.0;
  }
  if (d < 32) {
    const ushort* src = (d < 16) ? sh0 : sh1;
    ushort* dst = (d < 16) ? E0f : E1f;
    int p = d & 15, h = p & 1, ks = p >> 1;
    int slot = ((k >> 5) * 8 + ks) * 64 + (k & 31) + 32 * h;
    int off = ks * 16 + h * 8;
    uint32_t w0 = (uint32_t)src[off + 0] | ((uint32_t)src[off + 1] << 16);
    uint32_t w1 = (uint32_t)src[off + 2] | ((uint32_t)src[off + 3] << 16);
    uint32_t w2 = (uint32_t)src[off + 4] | ((uint32_t)src[off + 5] << 16);
    uint32_t w3 = (uint32_t)src[off + 6] | ((uint32_t)src[off + 7] << 16);
    uint4 val; val.x = w0; val.y = w1; val.z = w2; val.w = w3;
    *(uint4*)(dst + (size_t)slot * 8) = val;
  }
}

// Kernel A: transpose Z (B,D,L) -> zflat (N,D) row-major.
// Block = (b, l-tile of 32). LDS pad 33 breaks transpose bank conflicts to ~4-way.
__global__ __launch_bounds__(256) void k_zflat(const float* __restrict__ Z,
                                               float* __restrict__ zflat) {
  __shared__ float Zs[128][33];
  const int tid = threadIdx.x;
  const int b = blockIdx.x >> 7;        // 8 batches
  const int lt = blockIdx.x & 127;      // 128 l-tiles
  const int l0 = lt * 32;
  const float* zsrc = Z + (size_t)b * DD * LL + l0;
#pragma unroll
  for (int p = 0; p < 4; ++p) {
    int f = p * 256 + tid;
    int d = f >> 3;
    int q = f & 7;
    float4 v = *(const float4*)(zsrc + (size_t)d * LL + q * 4);
    Zs[d][q * 4 + 0] = v.x;
    Zs[d][q * 4 + 1] = v.y;
    Zs[d][q * 4 + 2] = v.z;
    Zs[d][q * 4 + 3] = v.w;
  }
  __syncthreads();
  float* dst = zflat + (size_t)(b * LL + l0) * DD;
#pragma unroll
  for (int p = 0; p < 4; ++p) {
    int f = p * 256 + tid;
    int row = f >> 5;
    int dq = f & 31;
    float4 v;
    v.x = Zs[dq * 4 + 0][row];
    v.y = Zs[dq * 4 + 1][row];
    v.z = Zs[dq * 4 + 2][row];
    v.w = Zs[dq * 4 + 3][row];
    *(float4*)(dst + (size_t)row * DD + dq * 4) = v;
  }
}

// Kernel 1: MFMA distance GEMM (bf16x2-split, 3 passes) + lane-local argmin +
// selective exact refine. Writes indices ONLY (no atomics).
__global__ __launch_bounds__(256) void k_dist(const float* __restrict__ Z,
                                              const float* __restrict__ E,
                                              const ushort* __restrict__ E0f,
                                              const ushort* __restrict__ E1f,
                                              const float* __restrict__ esq,
                                              int* __restrict__ idx_out) {
  __shared__ float Zt[128][128];   // [dim][row] fp32, 64 KB
  __shared__ float esh[1024];      // 4 KB

  const int tid = threadIdx.x;
  const int w = tid >> 6;
  const int lane = tid & 63;
  const int hi = lane >> 5;
  const int rr = lane & 31;
  const int rloc = w * 32 + rr;
  const int r0 = blockIdx.x * 128;
  const int b = r0 >> 12;
  const int l0 = r0 & (LL - 1);

  // stage Z tile (coalesced: 512B contiguous per dim)
  const float* zsrc = Z + (size_t)b * DD * LL + l0;
#pragma unroll
  for (int p = 0; p < 16; ++p) {
    int idx = p * 256 + tid;
    int d = idx >> 5;
    int g = idx & 31;
    float4 v = *(const float4*)(zsrc + (size_t)d * LL + g * 4);
    *(float4*)(&Zt[d][g * 4]) = v;
  }
  {  // stage esq
    float4 e4 = *(const float4*)(esq + tid * 4);
    *(float4*)(&esh[tid * 4]) = e4;
  }
  __syncthreads();

  // build B-frags (z bf16 splits): lane holds row rloc, dims ks*16+hi*8+j
  s16x8 B0[8], B1[8];
#pragma unroll
  for (int ks = 0; ks < 8; ++ks) {
    s16x8 b0, b1;
#pragma unroll
    for (int j = 0; j < 8; ++j) {
      float z = Zt[ks * 16 + hi * 8 + j][rloc];
      ushort h0 = f2bf(z);
      float z0f = bf2f(h0);
      ushort h1 = f2bf(z - z0f);
      b0[j] = (short)h0;
      b1[j] = (short)h1;
    }
    B0[ks] = b0; B1[ks] = b1;
  }
  // zsq (serial fma, matches prior passing kernels)
  float zsq = 0.0f;
  if (hi == 0) {
#pragma unroll 4
    for (int d = 0; d < 128; ++d) {
      float z = Zt[d][rloc];
      zsq = fmaf(z, z, zsq);
    }
  }
  zsq = __shfl(zsq, rr, 64);

  // main loop: 32 code-subtiles of 32
  float b1v = 3.4e38f, b2v = 3.4e38f;
  int b1i = 0, b2i = 0;
  const float4* e0p = (const float4*)E0f;
  const float4* e1p = (const float4*)E1f;

  for (int s = 0; s < 32; ++s) {
    f32x16 acc;
#pragma unroll
    for (int i = 0; i < 16; ++i) acc[i] = 0.0f;
    const int base = s * 8 * 64 + lane;
#pragma unroll
    for (int ks = 0; ks < 8; ++ks) {
      F4S8 ua, ub;
      ua.f = e0p[base + ks * 64];
      ub.f = e1p[base + ks * 64];
      acc = __builtin_amdgcn_mfma_f32_32x32x16_bf16(ua.s, B0[ks], acc, 0, 0, 0);
      acc = __builtin_amdgcn_mfma_f32_32x32x16_bf16(ua.s, B1[ks], acc, 0, 0, 0);
      acc = __builtin_amdgcn_mfma_f32_32x32x16_bf16(ub.s, B0[ks], acc, 0, 0, 0);
    }
    // finalize: lane-local codes, strictly increasing -> first-index tie-break
#pragma unroll
    for (int reg = 0; reg < 16; ++reg) {
      int cl = (reg & 3) + 8 * (reg >> 2) + 4 * hi;
      int c = s * 32 + cl;
      float rv = fmaf(-2.0f, acc[reg], esh[c]);   // zsq-free ranking key
      if (rv < b1v) { b2v = b1v; b2i = b1i; b1v = rv; b1i = c; }
      else if (rv < b2v) { b2v = rv; b2i = c; }
    }
  }

  // merge the two half-lanes (codes interleave -> lexicographic (val, idx))
  float ov1 = __shfl_xor(b1v, 32, 64); int oi1 = __shfl_xor(b1i, 32, 64);
  float ov2 = __shfl_xor(b2v, 32, 64); int oi2 = __shfl_xor(b2i, 32, 64);
  if (ov1 < b1v || (ov1 == b1v && oi1 < b1i)) { b2v = b1v; b2i = b1i; b1v = ov1; b1i = oi1; }
  else if (ov1 < b2v || (ov1 == b2v && oi1 < b2i)) { b2v = ov1; b2i = oi1; }
  if (ov2 < b2v || (ov2 == b2v && oi2 < b2i)) { b2v = ov2; b2i = oi2; }

  // selective exact refine (reference fp32 expression tree), ~1% of rows
  int fi = b1i;
  if (b2v - b1v <= 4e-5f) {
    float dot1 = 0.0f, dot2 = 0.0f;
    const float* e1r = E + (size_t)b1i * DD;
    const float* e2r = E + (size_t)b2i * DD;
    for (int d = 0; d < 128; ++d) {
      float z = Zt[d][rloc];
      dot1 = fmaf(z, e1r[d], dot1);
      dot2 = fmaf(z, e2r[d], dot2);
    }
    float k1 = (zsq + esh[b1i]) - 2.0f * dot1;
    float k2 = (zsq + esh[b2i]) - 2.0f * dot2;
    if (k2 < k1 || (k2 == k1 && b2i < b1i)) fi = b2i;
  }

  if (hi == 0) {
    idx_out[r0 + rloc] = fi;
  }
}

// Kernel B: gather-style segment sum. One block per code; scan indices,
// compact matches, gather zflat rows, reduce in registers. No atomics to HBM.
__global__ __launch_bounds__(256) void k_wsum(const float* __restrict__ zflat,
                                              const int* __restrict__ idxs,
                                              float* __restrict__ wsum,
                                              float* __restrict__ counts) {
  const int k = blockIdx.x;          // code id, 1024 blocks
  const int tid = threadIdx.x;
  __shared__ int list[4096];
  __shared__ int cnt;
  __shared__ float red[128];

  const int h = tid >> 7;            // 0/1
  const int d = tid & 127;
  float acc = 0.0f;
  int totalAll = 0;

  for (int seg = 0; seg < 8; ++seg) {   // 8 segments of 4096 rows
    if (tid == 0) cnt = 0;
    __syncthreads();
#pragma unroll
    for (int p = 0; p < 16; ++p) {
      int row = seg * 4096 + p * 256 + tid;
      if (idxs[row] == k) {
        int pos = atomicAdd(&cnt, 1);   // LDS atomic (order-free sum)
        list[pos] = row;
      }
    }
    __syncthreads();
    int m = cnt;
    for (int j = h; j < m; j += 2) {
      int row = list[j];
      acc += zflat[(size_t)row * DD + d];
    }
    totalAll += m;
    __syncthreads();   // protect list before next segment
  }

  if (h == 1) red[d] = acc;
  __syncthreads();
  if (h == 0) {
    wsum[k * DD + d] = acc + red[d];
    if (d == 0) counts[k] = (float)totalAll;
  }
}

// Kernel 2: cluster-size EMA, dead detection, threefry restart indices, smoothing
__global__ __launch_bounds__(1024) void k_cluster(const float* __restrict__ counts,
                                                  const float* __restrict__ cs_in,
                                                  float* __restrict__ smooth,
                                                  int* __restrict__ ridx,
                                                  int* __restrict__ deadf) {
  const int k = threadIdx.x;
  float c = counts[k];
  float t1 = 0.99f * cs_in[k];
  float t2 = 0.01f * c;
  float nc = t1 + t2;
  bool dead = nc < 0.5f;

  uint32_t bits;
#if THREEFRY_PARTITIONABLE
  {
    uint32_t o0, o1;
    threefry2x32(0u, 42u, 0u, (uint32_t)k, &o0, &o1);
    bits = o0 ^ o1;
  }
#else
  {
    uint32_t o0, o1;
    if (k < 512) { threefry2x32(0u, 42u, (uint32_t)k, (uint32_t)(k + 512), &o0, &o1); bits = o0; }
    else         { threefry2x32(0u, 42u, (uint32_t)(k - 512), (uint32_t)k, &o0, &o1); bits = o1; }
  }
#endif
  int r = (int)(bits & 0x7FFFu);

  float rep = dead ? 0.5f : nc;

  __shared__ float red[1024];
  red[k] = rep;
  __syncthreads();
  for (int s = 512; s > 0; s >>= 1) {
    if (k < s) red[k] += red[k + s];
    __syncthreads();
  }
  float n = red[0];

  float sm = ((rep + 1e-5f) / (n + 0.01024f)) * n;
  smooth[k] = sm;
  ridx[k] = r;
  deadf[k] = dead ? 1 : 0;
}

// Kernel 3: new embedding = (EMA avg or restart vec) / smoothed
__global__ __launch_bounds__(256) void k_emb(const float* __restrict__ wsum,
                                             const float* __restrict__ avg_in,
                                             const float* __restrict__ Z,
                                             const float* __restrict__ smooth,
                                             const int* __restrict__ ridx,
                                             const int* __restrict__ deadf,
                                             float* __restrict__ nemb) {
  int kd = blockIdx.x * 256 + threadIdx.x;
  int k = kd >> 7;
  int d = kd & (DD - 1);
  float t1 = 0.99f * avg_in[kd];
  float t2 = 0.01f * wsum[kd];
  float na = t1 + t2;
  if (deadf[k]) {
    int r = ridx[k];
    float zv = Z[((size_t)(r >> 12) * DD + d) * LL + (r & (LL - 1))];
    na = zv * 0.5f;
  }
  nemb[kd] = na / smooth[k];
}

// Kernel 4: gather z_q, write z_q_st + indices_map, accumulate squared-error
__global__ __launch_bounds__(256) void k_out(const float* __restrict__ Z,
                                             const float* __restrict__ nemb,
                                             const int* __restrict__ idxs,
                                             float* __restrict__ out,
                                             double* __restrict__ lacc) {
  int t = blockIdx.x * 256 + threadIdx.x;
  int l4 = t & (LL / 4 - 1);
  int d = (t >> 10) & (DD - 1);
  int b = t >> 17;
  size_t zoff = ((size_t)(b * DD + d)) * LL + (size_t)l4 * 4;
  const float4 ze = *(const float4*)(Z + zoff);
  int n0 = b * LL + l4 * 4;
  int i0 = idxs[n0 + 0], i1 = idxs[n0 + 1], i2 = idxs[n0 + 2], i3 = idxs[n0 + 3];
  float q0 = nemb[(size_t)i0 * DD + d];
  float q1 = nemb[(size_t)i1 * DD + d];
  float q2 = nemb[(size_t)i2 * DD + d];
  float q3 = nemb[(size_t)i3 * DD + d];
  float4 o;
  o.x = ze.x + (q0 - ze.x);
  o.y = ze.y + (q1 - ze.y);
  o.z = ze.z + (q2 - ze.z);
  o.w = ze.w + (q3 - ze.w);
  *(float4*)(out + zoff) = o;
  if (d == 0) {
    float* oi = out + (size_t)ZTOT;
    oi[n0 + 0] = (float)i0;
    oi[n0 + 1] = (float)i1;
    oi[n0 + 2] = (float)i2;
    oi[n0 + 3] = (float)i3;
  }
  float d0 = ze.x - q0, d1 = ze.y - q1, d2 = ze.z - q2, d3 = ze.w - q3;
  float s = d0 * d0 + d1 * d1 + d2 * d2 + d3 * d3;
  for (int off = 32; off > 0; off >>= 1) s += __shfl_down(s, off, 64);
  __shared__ float wsums[4];
  if ((threadIdx.x & 63) == 0) wsums[threadIdx.x >> 6] = s;
  __syncthreads();
  if (threadIdx.x == 0) {
    float tot = (wsums[0] + wsums[1]) + (wsums[2] + wsums[3]);
    atomicAdd(lacc, (double)tot);
  }
}

// Kernel 5: final loss scalars
__global__ void k_fin(const double* __restrict__ lacc, float* __restrict__ out) {
  double S = lacc[0];
  float cb = (float)(S / (double)ZTOT);
  float bc = 0.25f * cb;
  float vq = cb + bc;
  float* o = out + (size_t)ZTOT + NN;
  o[0] = vq;
  o[1] = cb;
  o[2] = bc;
}

extern "C" void kernel_launch(void* const* d_in, const int* in_sizes, int n_in,
                              void* d_out, int out_size, void* d_ws, size_t ws_size,
                              hipStream_t stream) {
  const float* Z  = (const float*)d_in[0];   // z_e        (8,128,4096)
  const float* E  = (const float*)d_in[1];   // embedding  (1024,128)
  const float* CS = (const float*)d_in[2];   // cluster_size (1024,)
  const float* EA = (const float*)d_in[3];   // embedding_avg (1024,128)
  float* out = (float*)d_out;
  float* ws = (float*)d_ws;

  float* counts = ws;                        // 1024
  float* esq    = ws + 1024;                 // 1024
  float* smooth = ws + 2048;                 // 1024
  int*   ridx   = (int*)(ws + 3072);         // 1024
  int*   deadf  = (int*)(ws + 4096);         // 1024
  float* wsum   = ws + 8192;                 // 131072
  float* nemb   = ws + 8192 + 131072;        // 131072 floats (512 KB)
  int*   idxs   = (int*)(ws + 270336);       // 32768
  double* lacc  = (double*)(ws + 303104);    // 8B aligned

  // bf16-split E fragment buffers (256 KB each) reuse the nemb slot:
  // consumed by k_dist, overwritten later by k_emb (stream-ordered).
  ushort* E0f = (ushort*)nemb;
  ushort* E1f = (ushort*)(nemb + 65536);

  // zflat (N,D) = 16.8 MB parked in d_out[0..ZTOT): consumed by k_wsum,
  // overwritten by k_out at the end (stream-ordered).
  float* zflat = out;

  k_prep<<<KC, DD, 0, stream>>>(E, esq, lacc, E0f, E1f);
  k_zflat<<<BB * (LL / 32), 256, 0, stream>>>(Z, zflat);
  k_dist<<<NN / 128, 256, 0, stream>>>(Z, E, E0f, E1f, esq, idxs);
  k_wsum<<<KC, 256, 0, stream>>>(zflat, idxs, wsum, counts);
  k_cluster<<<1, KC, 0, stream>>>(counts, CS, smooth, ridx, deadf);
  k_emb<<<(KC * DD) / 256, 256, 0, stream>>>(wsum, EA, Z, smooth, ridx, deadf, nemb);
  k_out<<<(ZTOT / 4) / 256, 256, 0, stream>>>(Z, nemb, idxs, out, lacc);
  k_fin<<<1, 1, 0, stream>>>(lacc, out);
}

// Round 10
// 156.076 us; speedup vs baseline: 2.7834x; 1.4904x over previous
//
#include <hip/hip_runtime.h>
#include <stdint.h>

// Problem constants (fixed by the reference)
constexpr int BB = 8;
constexpr int LL = 4096;
constexpr int DD = 128;
constexpr int KC = 1024;
constexpr int NN = BB * LL;          // 32768
constexpr int ZTOT = BB * DD * LL;   // 4194304

#define THREEFRY_PARTITIONABLE 1

typedef float f32x16 __attribute__((ext_vector_type(16)));
typedef short s16x8 __attribute__((ext_vector_type(8)));

union F4S8 { float4 f; s16x8 s; };

__device__ __forceinline__ ushort f2bf(float x) {   // RNE float->bf16
  uint32_t u = __float_as_uint(x);
  uint32_t r = u + 0x7FFFu + ((u >> 16) & 1u);
  return (ushort)(r >> 16);
}
__device__ __forceinline__ float bf2f(ushort h) {
  return __uint_as_float(((uint32_t)h) << 16);
}

__device__ __forceinline__ uint32_t rotl32(uint32_t x, int r) {
  return (x << r) | (x >> (32 - r));
}

__device__ __forceinline__ void threefry2x32(uint32_t k0, uint32_t k1,
                                             uint32_t x0, uint32_t x1,
                                             uint32_t* o0, uint32_t* o1) {
  uint32_t ks0 = k0, ks1 = k1, ks2 = 0x1BD11BDAu ^ k0 ^ k1;
  x0 += ks0; x1 += ks1;
  x0 += x1; x1 = rotl32(x1, 13); x1 ^= x0;
  x0 += x1; x1 = rotl32(x1, 15); x1 ^= x0;
  x0 += x1; x1 = rotl32(x1, 26); x1 ^= x0;
  x0 += x1; x1 = rotl32(x1, 6);  x1 ^= x0;
  x0 += ks1; x1 += ks2 + 1u;
  x0 += x1; x1 = rotl32(x1, 17); x1 ^= x0;
  x0 += x1; x1 = rotl32(x1, 29); x1 ^= x0;
  x0 += x1; x1 = rotl32(x1, 16); x1 ^= x0;
  x0 += x1; x1 = rotl32(x1, 24); x1 ^= x0;
  x0 += ks2; x1 += ks0 + 2u;
  x0 += x1; x1 = rotl32(x1, 13); x1 ^= x0;
  x0 += x1; x1 = rotl32(x1, 15); x1 ^= x0;
  x0 += x1; x1 = rotl32(x1, 26); x1 ^= x0;
  x0 += x1; x1 = rotl32(x1, 6);  x1 ^= x0;
  x0 += ks0; x1 += ks1 + 3u;
  x0 += x1; x1 = rotl32(x1, 17); x1 ^= x0;
  x0 += x1; x1 = rotl32(x1, 29); x1 ^= x0;
  x0 += x1; x1 = rotl32(x1, 16); x1 ^= x0;
  x0 += x1; x1 = rotl32(x1, 24); x1 ^= x0;
  x0 += ks1; x1 += ks2 + 4u;
  x0 += x1; x1 = rotl32(x1, 13); x1 ^= x0;
  x0 += x1; x1 = rotl32(x1, 15); x1 ^= x0;
  x0 += x1; x1 = rotl32(x1, 26); x1 ^= x0;
  x0 += x1; x1 = rotl32(x1, 6);  x1 ^= x0;
  x0 += ks2; x1 += ks0 + 5u;
  *o0 = x0; *o1 = x1;
}

// Kernel 0: e_sq per code, bf16-split E fragments (MFMA A-layout linear), lacc init.
// Frag layout: slot = ((k>>5)*8 + ks)*64 + (k&31) + 32*h ; 8 bf16 = dims ks*16+h*8+j.
__global__ __launch_bounds__(128) void k_prep(const float* __restrict__ E,
                                              float* __restrict__ esq,
                                              double* __restrict__ lacc,
                                              ushort* __restrict__ E0f,
                                              ushort* __restrict__ E1f) {
  const int k = blockIdx.x;       // code
  const int d = threadIdx.x;      // dim
  float v = E[k * DD + d];
  __shared__ float r[128];
  __shared__ ushort sh0[128], sh1[128];
  ushort h0 = f2bf(v);
  float v0 = bf2f(h0);
  ushort h1 = f2bf(v - v0);
  sh0[d] = h0; sh1[d] = h1;
  r[d] = v * v;
  __syncthreads();
  for (int s = 64; s > 0; s >>= 1) {
    if (d < s) r[d] += r[d + s];
    __syncthreads();
  }
  if (d == 0) {
    esq[k] = r[0];
    if (k == 0) lacc[0] = 0.0;
  }
  if (d < 32) {
    const ushort* src = (d < 16) ? sh0 : sh1;
    ushort* dst = (d < 16) ? E0f : E1f;
    int p = d & 15, h = p & 1, ks = p >> 1;
    int slot = ((k >> 5) * 8 + ks) * 64 + (k & 31) + 32 * h;
    int off = ks * 16 + h * 8;
    uint32_t w0 = (uint32_t)src[off + 0] | ((uint32_t)src[off + 1] << 16);
    uint32_t w1 = (uint32_t)src[off + 2] | ((uint32_t)src[off + 3] << 16);
    uint32_t w2 = (uint32_t)src[off + 4] | ((uint32_t)src[off + 5] << 16);
    uint32_t w3 = (uint32_t)src[off + 6] | ((uint32_t)src[off + 7] << 16);
    uint4 val; val.x = w0; val.y = w1; val.z = w2; val.w = w3;
    *(uint4*)(dst + (size_t)slot * 8) = val;
  }
}

// Kernel 1: MFMA distance argmin, 4-way code-split across waves for occupancy.
// Block: 256 thr = 4 waves; 32 rows/block; wave w scans codes [w*256,(w+1)*256).
// Also emits zflat (N,D) transposed rows (fused, replaces k_zflat).
__global__ __launch_bounds__(256, 4) void k_dist(const float* __restrict__ Z,
                                                 const float* __restrict__ E,
                                                 const ushort* __restrict__ E0f,
                                                 const ushort* __restrict__ E1f,
                                                 const float* __restrict__ esq,
                                                 int* __restrict__ idx_out,
                                                 float* __restrict__ zflat) {
  __shared__ float Zt[128][33];    // [dim][row], pad 33: frag reads conflict-free
  __shared__ float esh[1024];      // 4 KB
  __shared__ float mv1[4][32], mv2[4][32];
  __shared__ int   mi1[4][32], mi2[4][32];

  const int tid = threadIdx.x;
  const int w = tid >> 6;          // wave id = code-split id
  const int lane = tid & 63;
  const int hi = lane >> 5;
  const int rr = lane & 31;
  const int r0 = blockIdx.x * 32;
  const int b = r0 >> 12;
  const int l0 = r0 & (LL - 1);

  // stage Z tile (32 rows): per dim, 128B contiguous
  const float* zsrc = Z + (size_t)b * DD * LL + l0;
#pragma unroll
  for (int p = 0; p < 4; ++p) {
    int f = p * 256 + tid;
    int d = f >> 3;
    int g = f & 7;
    float4 v = *(const float4*)(zsrc + (size_t)d * LL + g * 4);
    Zt[d][g * 4 + 0] = v.x;
    Zt[d][g * 4 + 1] = v.y;
    Zt[d][g * 4 + 2] = v.z;
    Zt[d][g * 4 + 3] = v.w;
  }
  {  // stage esq
    float4 e4 = *(const float4*)(esq + tid * 4);
    *(float4*)(&esh[tid * 4]) = e4;
  }
  __syncthreads();

  // fused zflat write: rows r0..r0+31 in (N,D) row-major
  {
    float* dst = zflat + (size_t)r0 * DD;
#pragma unroll
    for (int p = 0; p < 4; ++p) {
      int f = p * 256 + tid;
      int row = f >> 5;
      int dq = f & 31;
      float4 v;
      v.x = Zt[dq * 4 + 0][row];
      v.y = Zt[dq * 4 + 1][row];
      v.z = Zt[dq * 4 + 2][row];
      v.w = Zt[dq * 4 + 3][row];
      *(float4*)(dst + (size_t)row * DD + dq * 4) = v;
    }
  }

  // build B-frags (z bf16 splits): lane holds row rr, dims ks*16+hi*8+j
  s16x8 B0[8], B1[8];
#pragma unroll
  for (int ks = 0; ks < 8; ++ks) {
    s16x8 b0, b1;
#pragma unroll
    for (int j = 0; j < 8; ++j) {
      float z = Zt[ks * 16 + hi * 8 + j][rr];
      ushort h0 = f2bf(z);
      float z0f = bf2f(h0);
      ushort h1 = f2bf(z - z0f);
      b0[j] = (short)h0;
      b1[j] = (short)h1;
    }
    B0[ks] = b0; B1[ks] = b1;
  }

  // wave scans its 8 code-subtiles (codes w*256 .. w*256+255, ascending)
  float b1v = 3.4e38f, b2v = 3.4e38f;
  int b1i = 0, b2i = 0;
  const float4* e0p = (const float4*)E0f;
  const float4* e1p = (const float4*)E1f;

  for (int s = 0; s < 8; ++s) {
    const int sg = w * 8 + s;        // global subtile
    f32x16 acc;
#pragma unroll
    for (int i = 0; i < 16; ++i) acc[i] = 0.0f;
    const int base = sg * 512 + lane;
#pragma unroll
    for (int ks = 0; ks < 8; ++ks) {
      F4S8 ua, ub;
      ua.f = e0p[base + ks * 64];
      ub.f = e1p[base + ks * 64];
      acc = __builtin_amdgcn_mfma_f32_32x32x16_bf16(ua.s, B0[ks], acc, 0, 0, 0);
      acc = __builtin_amdgcn_mfma_f32_32x32x16_bf16(ua.s, B1[ks], acc, 0, 0, 0);
      acc = __builtin_amdgcn_mfma_f32_32x32x16_bf16(ub.s, B0[ks], acc, 0, 0, 0);
    }
    // finalize: lane-local codes, ascending -> first-index tie-break
#pragma unroll
    for (int reg = 0; reg < 16; ++reg) {
      int cl = (reg & 3) + 8 * (reg >> 2) + 4 * hi;
      int c = sg * 32 + cl;
      float rv = fmaf(-2.0f, acc[reg], esh[c]);   // zsq-free ranking key
      if (rv < b1v) { b2v = b1v; b2i = b1i; b1v = rv; b1i = c; }
      else if (rv < b2v) { b2v = rv; b2i = c; }
    }
  }

  // merge the two half-lanes (codes interleave -> lexicographic (val, idx))
  float ov1 = __shfl_xor(b1v, 32, 64); int oi1 = __shfl_xor(b1i, 32, 64);
  float ov2 = __shfl_xor(b2v, 32, 64); int oi2 = __shfl_xor(b2i, 32, 64);
  if (ov1 < b1v || (ov1 == b1v && oi1 < b1i)) { b2v = b1v; b2i = b1i; b1v = ov1; b1i = oi1; }
  else if (ov1 < b2v || (ov1 == b2v && oi1 < b2i)) { b2v = ov1; b2i = oi1; }
  if (ov2 < b2v || (ov2 == b2v && oi2 < b2i)) { b2v = ov2; b2i = oi2; }

  if (hi == 0) {
    mv1[w][rr] = b1v; mi1[w][rr] = b1i;
    mv2[w][rr] = b2v; mi2[w][rr] = b2i;
  }
  __syncthreads();

  // final merge across 4 waves + selective exact refine, one thread per row
  if (tid < 32) {
    const int row = tid;
    float fb1 = mv1[0][row]; int fi1 = mi1[0][row];
    float fb2 = mv2[0][row]; int fi2 = mi2[0][row];
#pragma unroll
    for (int q = 1; q < 4; ++q) {
      float v1 = mv1[q][row]; int i1 = mi1[q][row];
      float v2 = mv2[q][row]; int i2 = mi2[q][row];
      if (v1 < fb1 || (v1 == fb1 && i1 < fi1)) {
        fb2 = fb1; fi2 = fi1; fb1 = v1; fi1 = i1;
      } else if (v1 < fb2 || (v1 == fb2 && i1 < fi2)) {
        fb2 = v1; fi2 = i1;
      }
      if (v2 < fb2 || (v2 == fb2 && i2 < fi2)) { fb2 = v2; fi2 = i2; }
    }

    int fi = fi1;
    if (fb2 - fb1 <= 4e-5f) {
      float zsq = 0.0f;
#pragma unroll 4
      for (int d = 0; d < 128; ++d) {
        float z = Zt[d][row];
        zsq = fmaf(z, z, zsq);
      }
      float dot1 = 0.0f, dot2 = 0.0f;
      const float* e1r = E + (size_t)fi1 * DD;
      const float* e2r = E + (size_t)fi2 * DD;
      for (int d = 0; d < 128; ++d) {
        float z = Zt[d][row];
        dot1 = fmaf(z, e1r[d], dot1);
        dot2 = fmaf(z, e2r[d], dot2);
      }
      float k1 = (zsq + esh[fi1]) - 2.0f * dot1;
      float k2 = (zsq + esh[fi2]) - 2.0f * dot2;
      if (k2 < k1 || (k2 == k1 && fi2 < fi1)) fi = fi2;
    }
    idx_out[r0 + row] = fi;
  }
}

// Kernel B: gather-style segment sum. One block per code; scan indices,
// compact matches, gather zflat rows, reduce in registers. No atomics to HBM.
__global__ __launch_bounds__(256) void k_wsum(const float* __restrict__ zflat,
                                              const int* __restrict__ idxs,
                                              float* __restrict__ wsum,
                                              float* __restrict__ counts) {
  const int k = blockIdx.x;          // code id, 1024 blocks
  const int tid = threadIdx.x;
  __shared__ int list[4096];
  __shared__ int cnt;
  __shared__ float red[128];

  const int h = tid >> 7;            // 0/1
  const int d = tid & 127;
  float acc = 0.0f;
  int totalAll = 0;

  for (int seg = 0; seg < 8; ++seg) {   // 8 segments of 4096 rows
    if (tid == 0) cnt = 0;
    __syncthreads();
#pragma unroll
    for (int p = 0; p < 16; ++p) {
      int row = seg * 4096 + p * 256 + tid;
      if (idxs[row] == k) {
        int pos = atomicAdd(&cnt, 1);   // LDS atomic (order-free sum)
        list[pos] = row;
      }
    }
    __syncthreads();
    int m = cnt;
    for (int j = h; j < m; j += 2) {
      int row = list[j];
      acc += zflat[(size_t)row * DD + d];
    }
    totalAll += m;
    __syncthreads();   // protect list before next segment
  }

  if (h == 1) red[d] = acc;
  __syncthreads();
  if (h == 0) {
    wsum[k * DD + d] = acc + red[d];
    if (d == 0) counts[k] = (float)totalAll;
  }
}

// Kernel 2: cluster-size EMA, dead detection, threefry restart indices, smoothing
__global__ __launch_bounds__(1024) void k_cluster(const float* __restrict__ counts,
                                                  const float* __restrict__ cs_in,
                                                  float* __restrict__ smooth,
                                                  int* __restrict__ ridx,
                                                  int* __restrict__ deadf) {
  const int k = threadIdx.x;
  float c = counts[k];
  float t1 = 0.99f * cs_in[k];
  float t2 = 0.01f * c;
  float nc = t1 + t2;
  bool dead = nc < 0.5f;

  uint32_t bits;
#if THREEFRY_PARTITIONABLE
  {
    uint32_t o0, o1;
    threefry2x32(0u, 42u, 0u, (uint32_t)k, &o0, &o1);
    bits = o0 ^ o1;
  }
#else
  {
    uint32_t o0, o1;
    if (k < 512) { threefry2x32(0u, 42u, (uint32_t)k, (uint32_t)(k + 512), &o0, &o1); bits = o0; }
    else         { threefry2x32(0u, 42u, (uint32_t)(k - 512), (uint32_t)k, &o0, &o1); bits = o1; }
  }
#endif
  int r = (int)(bits & 0x7FFFu);

  float rep = dead ? 0.5f : nc;

  __shared__ float red[1024];
  red[k] = rep;
  __syncthreads();
  for (int s = 512; s > 0; s >>= 1) {
    if (k < s) red[k] += red[k + s];
    __syncthreads();
  }
  float n = red[0];

  float sm = ((rep + 1e-5f) / (n + 0.01024f)) * n;
  smooth[k] = sm;
  ridx[k] = r;
  deadf[k] = dead ? 1 : 0;
}

// Kernel 3: new embedding = (EMA avg or restart vec) / smoothed
__global__ __launch_bounds__(256) void k_emb(const float* __restrict__ wsum,
                                             const float* __restrict__ avg_in,
                                             const float* __restrict__ Z,
                                             const float* __restrict__ smooth,
                                             const int* __restrict__ ridx,
                                             const int* __restrict__ deadf,
                                             float* __restrict__ nemb) {
  int kd = blockIdx.x * 256 + threadIdx.x;
  int k = kd >> 7;
  int d = kd & (DD - 1);
  float t1 = 0.99f * avg_in[kd];
  float t2 = 0.01f * wsum[kd];
  float na = t1 + t2;
  if (deadf[k]) {
    int r = ridx[k];
    float zv = Z[((size_t)(r >> 12) * DD + d) * LL + (r & (LL - 1))];
    na = zv * 0.5f;
  }
  nemb[kd] = na / smooth[k];
}

// Kernel 4: gather z_q, write z_q_st + indices_map, accumulate squared-error
__global__ __launch_bounds__(256) void k_out(const float* __restrict__ Z,
                                             const float* __restrict__ nemb,
                                             const int* __restrict__ idxs,
                                             float* __restrict__ out,
                                             double* __restrict__ lacc) {
  int t = blockIdx.x * 256 + threadIdx.x;
  int l4 = t & (LL / 4 - 1);
  int d = (t >> 10) & (DD - 1);
  int b = t >> 17;
  size_t zoff = ((size_t)(b * DD + d)) * LL + (size_t)l4 * 4;
  const float4 ze = *(const float4*)(Z + zoff);
  int n0 = b * LL + l4 * 4;
  int i0 = idxs[n0 + 0], i1 = idxs[n0 + 1], i2 = idxs[n0 + 2], i3 = idxs[n0 + 3];
  float q0 = nemb[(size_t)i0 * DD + d];
  float q1 = nemb[(size_t)i1 * DD + d];
  float q2 = nemb[(size_t)i2 * DD + d];
  float q3 = nemb[(size_t)i3 * DD + d];
  float4 o;
  o.x = ze.x + (q0 - ze.x);
  o.y = ze.y + (q1 - ze.y);
  o.z = ze.z + (q2 - ze.z);
  o.w = ze.w + (q3 - ze.w);
  *(float4*)(out + zoff) = o;
  if (d == 0) {
    float* oi = out + (size_t)ZTOT;
    oi[n0 + 0] = (float)i0;
    oi[n0 + 1] = (float)i1;
    oi[n0 + 2] = (float)i2;
    oi[n0 + 3] = (float)i3;
  }
  float d0 = ze.x - q0, d1 = ze.y - q1, d2 = ze.z - q2, d3 = ze.w - q3;
  float s = d0 * d0 + d1 * d1 + d2 * d2 + d3 * d3;
  for (int off = 32; off > 0; off >>= 1) s += __shfl_down(s, off, 64);
  __shared__ float wsums[4];
  if ((threadIdx.x & 63) == 0) wsums[threadIdx.x >> 6] = s;
  __syncthreads();
  if (threadIdx.x == 0) {
    float tot = (wsums[0] + wsums[1]) + (wsums[2] + wsums[3]);
    atomicAdd(lacc, (double)tot);
  }
}

// Kernel 5: final loss scalars
__global__ void k_fin(const double* __restrict__ lacc, float* __restrict__ out) {
  double S = lacc[0];
  float cb = (float)(S / (double)ZTOT);
  float bc = 0.25f * cb;
  float vq = cb + bc;
  float* o = out + (size_t)ZTOT + NN;
  o[0] = vq;
  o[1] = cb;
  o[2] = bc;
}

extern "C" void kernel_launch(void* const* d_in, const int* in_sizes, int n_in,
                              void* d_out, int out_size, void* d_ws, size_t ws_size,
                              hipStream_t stream) {
  const float* Z  = (const float*)d_in[0];   // z_e        (8,128,4096)
  const float* E  = (const float*)d_in[1];   // embedding  (1024,128)
  const float* CS = (const float*)d_in[2];   // cluster_size (1024,)
  const float* EA = (const float*)d_in[3];   // embedding_avg (1024,128)
  float* out = (float*)d_out;
  float* ws = (float*)d_ws;

  float* counts = ws;                        // 1024
  float* esq    = ws + 1024;                 // 1024
  float* smooth = ws + 2048;                 // 1024
  int*   ridx   = (int*)(ws + 3072);         // 1024
  int*   deadf  = (int*)(ws + 4096);         // 1024
  float* wsum   = ws + 8192;                 // 131072
  float* nemb   = ws + 8192 + 131072;        // 131072 floats (512 KB)
  int*   idxs   = (int*)(ws + 270336);       // 32768
  double* lacc  = (double*)(ws + 303104);    // 8B aligned

  // bf16-split E fragment buffers (256 KB each) reuse the nemb slot:
  // consumed by k_dist, overwritten later by k_emb (stream-ordered).
  ushort* E0f = (ushort*)nemb;
  ushort* E1f = (ushort*)(nemb + 65536);

  // zflat (N,D) = 16.8 MB parked in d_out[0..ZTOT): written by k_dist (fused
  // transpose), consumed by k_wsum, overwritten by k_out (stream-ordered).
  float* zflat = out;

  k_prep<<<KC, DD, 0, stream>>>(E, esq, lacc, E0f, E1f);
  k_dist<<<NN / 32, 256, 0, stream>>>(Z, E, E0f, E1f, esq, idxs, zflat);
  k_wsum<<<KC, 256, 0, stream>>>(zflat, idxs, wsum, counts);
  k_cluster<<<1, KC, 0, stream>>>(counts, CS, smooth, ridx, deadf);
  k_emb<<<(KC * DD) / 256, 256, 0, stream>>>(wsum, EA, Z, smooth, ridx, deadf, nemb);
  k_out<<<(ZTOT / 4) / 256, 256, 0, stream>>>(Z, nemb, idxs, out, lacc);
  k_fin<<<1, 1, 0, stream>>>(lacc, out);
}

// Round 11
// 118.275 us; speedup vs baseline: 3.6729x; 1.3196x over previous
//
#include <hip/hip_runtime.h>
#include <stdint.h>

// Problem constants (fixed by the reference)
constexpr int BB = 8;
constexpr int LL = 4096;
constexpr int DD = 128;
constexpr int KC = 1024;
constexpr int NN = BB * LL;          // 32768
constexpr int ZTOT = BB * DD * LL;   // 4194304

#define THREEFRY_PARTITIONABLE 1

typedef float f32x16 __attribute__((ext_vector_type(16)));
typedef short s16x8 __attribute__((ext_vector_type(8)));

union F4S8 { float4 f; s16x8 s; };

__device__ __forceinline__ ushort f2bf(float x) {   // RNE float->bf16
  uint32_t u = __float_as_uint(x);
  uint32_t r = u + 0x7FFFu + ((u >> 16) & 1u);
  return (ushort)(r >> 16);
}
__device__ __forceinline__ float bf2f(ushort h) {
  return __uint_as_float(((uint32_t)h) << 16);
}

__device__ __forceinline__ uint32_t rotl32(uint32_t x, int r) {
  return (x << r) | (x >> (32 - r));
}

__device__ __forceinline__ void threefry2x32(uint32_t k0, uint32_t k1,
                                             uint32_t x0, uint32_t x1,
                                             uint32_t* o0, uint32_t* o1) {
  uint32_t ks0 = k0, ks1 = k1, ks2 = 0x1BD11BDAu ^ k0 ^ k1;
  x0 += ks0; x1 += ks1;
  x0 += x1; x1 = rotl32(x1, 13); x1 ^= x0;
  x0 += x1; x1 = rotl32(x1, 15); x1 ^= x0;
  x0 += x1; x1 = rotl32(x1, 26); x1 ^= x0;
  x0 += x1; x1 = rotl32(x1, 6);  x1 ^= x0;
  x0 += ks1; x1 += ks2 + 1u;
  x0 += x1; x1 = rotl32(x1, 17); x1 ^= x0;
  x0 += x1; x1 = rotl32(x1, 29); x1 ^= x0;
  x0 += x1; x1 = rotl32(x1, 16); x1 ^= x0;
  x0 += x1; x1 = rotl32(x1, 24); x1 ^= x0;
  x0 += ks2; x1 += ks0 + 2u;
  x0 += x1; x1 = rotl32(x1, 13); x1 ^= x0;
  x0 += x1; x1 = rotl32(x1, 15); x1 ^= x0;
  x0 += x1; x1 = rotl32(x1, 26); x1 ^= x0;
  x0 += x1; x1 = rotl32(x1, 6);  x1 ^= x0;
  x0 += ks0; x1 += ks1 + 3u;
  x0 += x1; x1 = rotl32(x1, 17); x1 ^= x0;
  x0 += x1; x1 = rotl32(x1, 29); x1 ^= x0;
  x0 += x1; x1 = rotl32(x1, 16); x1 ^= x0;
  x0 += x1; x1 = rotl32(x1, 24); x1 ^= x0;
  x0 += ks1; x1 += ks2 + 4u;
  x0 += x1; x1 = rotl32(x1, 13); x1 ^= x0;
  x0 += x1; x1 = rotl32(x1, 15); x1 ^= x0;
  x0 += x1; x1 = rotl32(x1, 26); x1 ^= x0;
  x0 += x1; x1 = rotl32(x1, 6);  x1 ^= x0;
  x0 += ks2; x1 += ks0 + 5u;
  *o0 = x0; *o1 = x1;
}

// Kernel 0: e_sq per code, bf16-split E fragments (MFMA A-layout linear), lacc init.
// Frag layout: slot = ((k>>5)*8 + ks)*64 + (k&31) + 32*h ; 8 bf16 = dims ks*16+h*8+j.
__global__ __launch_bounds__(128) void k_prep(const float* __restrict__ E,
                                              float* __restrict__ esq,
                                              double* __restrict__ lacc,
                                              ushort* __restrict__ E0f,
                                              ushort* __restrict__ E1f) {
  const int k = blockIdx.x;       // code
  const int d = threadIdx.x;      // dim
  float v = E[k * DD + d];
  __shared__ float r[128];
  __shared__ ushort sh0[128], sh1[128];
  ushort h0 = f2bf(v);
  float v0 = bf2f(h0);
  ushort h1 = f2bf(v - v0);
  sh0[d] = h0; sh1[d] = h1;
  r[d] = v * v;
  __syncthreads();
  for (int s = 64; s > 0; s >>= 1) {
    if (d < s) r[d] += r[d + s];
    __syncthreads();
  }
  if (d == 0) {
    esq[k] = r[0];
    if (k == 0) lacc[0] = 0.0;
  }
  if (d < 32) {
    const ushort* src = (d < 16) ? sh0 : sh1;
    ushort* dst = (d < 16) ? E0f : E1f;
    int p = d & 15, h = p & 1, ks = p >> 1;
    int slot = ((k >> 5) * 8 + ks) * 64 + (k & 31) + 32 * h;
    int off = ks * 16 + h * 8;
    uint32_t w0 = (uint32_t)src[off + 0] | ((uint32_t)src[off + 1] << 16);
    uint32_t w1 = (uint32_t)src[off + 2] | ((uint32_t)src[off + 3] << 16);
    uint32_t w2 = (uint32_t)src[off + 4] | ((uint32_t)src[off + 5] << 16);
    uint32_t w3 = (uint32_t)src[off + 6] | ((uint32_t)src[off + 7] << 16);
    uint4 val; val.x = w0; val.y = w1; val.z = w2; val.w = w3;
    *(uint4*)(dst + (size_t)slot * 8) = val;
  }
}

// Kernel 1: MFMA distance argmin, 4-way code-split across waves for occupancy.
// Block: 256 thr = 4 waves; 32 rows/block; wave w scans codes [w*256,(w+1)*256).
// Also emits zflat (N,D) transposed rows (fused).
__global__ __launch_bounds__(256, 4) void k_dist(const float* __restrict__ Z,
                                                 const float* __restrict__ E,
                                                 const ushort* __restrict__ E0f,
                                                 const ushort* __restrict__ E1f,
                                                 const float* __restrict__ esq,
                                                 int* __restrict__ idx_out,
                                                 float* __restrict__ zflat) {
  __shared__ float Zt[128][33];    // [dim][row], pad 33: frag reads conflict-free
  __shared__ float esh[1024];      // 4 KB
  __shared__ float mv1[4][32], mv2[4][32];
  __shared__ int   mi1[4][32], mi2[4][32];

  const int tid = threadIdx.x;
  const int w = tid >> 6;          // wave id = code-split id
  const int lane = tid & 63;
  const int hi = lane >> 5;
  const int rr = lane & 31;
  const int r0 = blockIdx.x * 32;
  const int b = r0 >> 12;
  const int l0 = r0 & (LL - 1);

  // stage Z tile (32 rows): per dim, 128B contiguous
  const float* zsrc = Z + (size_t)b * DD * LL + l0;
#pragma unroll
  for (int p = 0; p < 4; ++p) {
    int f = p * 256 + tid;
    int d = f >> 3;
    int g = f & 7;
    float4 v = *(const float4*)(zsrc + (size_t)d * LL + g * 4);
    Zt[d][g * 4 + 0] = v.x;
    Zt[d][g * 4 + 1] = v.y;
    Zt[d][g * 4 + 2] = v.z;
    Zt[d][g * 4 + 3] = v.w;
  }
  {  // stage esq
    float4 e4 = *(const float4*)(esq + tid * 4);
    *(float4*)(&esh[tid * 4]) = e4;
  }
  __syncthreads();

  // fused zflat write: rows r0..r0+31 in (N,D) row-major
  {
    float* dst = zflat + (size_t)r0 * DD;
#pragma unroll
    for (int p = 0; p < 4; ++p) {
      int f = p * 256 + tid;
      int row = f >> 5;
      int dq = f & 31;
      float4 v;
      v.x = Zt[dq * 4 + 0][row];
      v.y = Zt[dq * 4 + 1][row];
      v.z = Zt[dq * 4 + 2][row];
      v.w = Zt[dq * 4 + 3][row];
      *(float4*)(dst + (size_t)row * DD + dq * 4) = v;
    }
  }

  // build B-frags (z bf16 splits): lane holds row rr, dims ks*16+hi*8+j
  s16x8 B0[8], B1[8];
#pragma unroll
  for (int ks = 0; ks < 8; ++ks) {
    s16x8 b0, b1;
#pragma unroll
    for (int j = 0; j < 8; ++j) {
      float z = Zt[ks * 16 + hi * 8 + j][rr];
      ushort h0 = f2bf(z);
      float z0f = bf2f(h0);
      ushort h1 = f2bf(z - z0f);
      b0[j] = (short)h0;
      b1[j] = (short)h1;
    }
    B0[ks] = b0; B1[ks] = b1;
  }

  // wave scans its 8 code-subtiles (codes w*256 .. w*256+255, ascending)
  float b1v = 3.4e38f, b2v = 3.4e38f;
  int b1i = 0, b2i = 0;
  const float4* e0p = (const float4*)E0f;
  const float4* e1p = (const float4*)E1f;

  for (int s = 0; s < 8; ++s) {
    const int sg = w * 8 + s;        // global subtile
    f32x16 acc;
#pragma unroll
    for (int i = 0; i < 16; ++i) acc[i] = 0.0f;
    const int base = sg * 512 + lane;
#pragma unroll
    for (int ks = 0; ks < 8; ++ks) {
      F4S8 ua, ub;
      ua.f = e0p[base + ks * 64];
      ub.f = e1p[base + ks * 64];
      acc = __builtin_amdgcn_mfma_f32_32x32x16_bf16(ua.s, B0[ks], acc, 0, 0, 0);
      acc = __builtin_amdgcn_mfma_f32_32x32x16_bf16(ua.s, B1[ks], acc, 0, 0, 0);
      acc = __builtin_amdgcn_mfma_f32_32x32x16_bf16(ub.s, B0[ks], acc, 0, 0, 0);
    }
    // finalize: lane-local codes, ascending -> first-index tie-break
#pragma unroll
    for (int reg = 0; reg < 16; ++reg) {
      int cl = (reg & 3) + 8 * (reg >> 2) + 4 * hi;
      int c = sg * 32 + cl;
      float rv = fmaf(-2.0f, acc[reg], esh[c]);   // zsq-free ranking key
      if (rv < b1v) { b2v = b1v; b2i = b1i; b1v = rv; b1i = c; }
      else if (rv < b2v) { b2v = rv; b2i = c; }
    }
  }

  // merge the two half-lanes (codes interleave -> lexicographic (val, idx))
  float ov1 = __shfl_xor(b1v, 32, 64); int oi1 = __shfl_xor(b1i, 32, 64);
  float ov2 = __shfl_xor(b2v, 32, 64); int oi2 = __shfl_xor(b2i, 32, 64);
  if (ov1 < b1v || (ov1 == b1v && oi1 < b1i)) { b2v = b1v; b2i = b1i; b1v = ov1; b1i = oi1; }
  else if (ov1 < b2v || (ov1 == b2v && oi1 < b2i)) { b2v = ov1; b2i = oi1; }
  if (ov2 < b2v || (ov2 == b2v && oi2 < b2i)) { b2v = ov2; b2i = oi2; }

  if (hi == 0) {
    mv1[w][rr] = b1v; mi1[w][rr] = b1i;
    mv2[w][rr] = b2v; mi2[w][rr] = b2i;
  }
  __syncthreads();

  // final merge across 4 waves + selective exact refine, one thread per row
  if (tid < 32) {
    const int row = tid;
    float fb1 = mv1[0][row]; int fi1 = mi1[0][row];
    float fb2 = mv2[0][row]; int fi2 = mi2[0][row];
#pragma unroll
    for (int q = 1; q < 4; ++q) {
      float v1 = mv1[q][row]; int i1 = mi1[q][row];
      float v2 = mv2[q][row]; int i2 = mi2[q][row];
      if (v1 < fb1 || (v1 == fb1 && i1 < fi1)) {
        fb2 = fb1; fi2 = fi1; fb1 = v1; fi1 = i1;
      } else if (v1 < fb2 || (v1 == fb2 && i1 < fi2)) {
        fb2 = v1; fi2 = i1;
      }
      if (v2 < fb2 || (v2 == fb2 && i2 < fi2)) { fb2 = v2; fi2 = i2; }
    }

    int fi = fi1;
    if (fb2 - fb1 <= 4e-5f) {
      float zsq = 0.0f;
#pragma unroll 4
      for (int d = 0; d < 128; ++d) {
        float z = Zt[d][row];
        zsq = fmaf(z, z, zsq);
      }
      float dot1 = 0.0f, dot2 = 0.0f;
      const float* e1r = E + (size_t)fi1 * DD;
      const float* e2r = E + (size_t)fi2 * DD;
      for (int d = 0; d < 128; ++d) {
        float z = Zt[d][row];
        dot1 = fmaf(z, e1r[d], dot1);
        dot2 = fmaf(z, e2r[d], dot2);
      }
      float k1 = (zsq + esh[fi1]) - 2.0f * dot1;
      float k2 = (zsq + esh[fi2]) - 2.0f * dot2;
      if (k2 < k1 || (k2 == k1 && fi2 < fi1)) fi = fi2;
    }
    idx_out[r0 + row] = fi;
  }
}

// Kernel B: gather-style segment sum. One block per code; scan indices,
// compact matches, gather zflat rows, reduce in registers. No atomics to HBM.
__global__ __launch_bounds__(256) void k_wsum(const float* __restrict__ zflat,
                                              const int* __restrict__ idxs,
                                              float* __restrict__ wsum,
                                              float* __restrict__ counts) {
  const int k = blockIdx.x;          // code id, 1024 blocks
  const int tid = threadIdx.x;
  __shared__ int list[4096];
  __shared__ int cnt;
  __shared__ float red[128];

  const int h = tid >> 7;            // 0/1
  const int d = tid & 127;
  float acc = 0.0f;
  int totalAll = 0;

  for (int seg = 0; seg < 8; ++seg) {   // 8 segments of 4096 rows
    if (tid == 0) cnt = 0;
    __syncthreads();
#pragma unroll
    for (int p = 0; p < 16; ++p) {
      int row = seg * 4096 + p * 256 + tid;
      if (idxs[row] == k) {
        int pos = atomicAdd(&cnt, 1);   // LDS atomic (order-free sum)
        list[pos] = row;
      }
    }
    __syncthreads();
    int m = cnt;
    for (int j = h; j < m; j += 2) {
      int row = list[j];
      acc += zflat[(size_t)row * DD + d];
    }
    totalAll += m;
    __syncthreads();   // protect list before next segment
  }

  if (h == 1) red[d] = acc;
  __syncthreads();
  if (h == 0) {
    wsum[k * DD + d] = acc + red[d];
    if (d == 0) counts[k] = (float)totalAll;
  }
}

// Kernel 2: cluster-size EMA, dead detection, threefry restart indices, smoothing
__global__ __launch_bounds__(1024) void k_cluster(const float* __restrict__ counts,
                                                  const float* __restrict__ cs_in,
                                                  float* __restrict__ smooth,
                                                  int* __restrict__ ridx,
                                                  int* __restrict__ deadf) {
  const int k = threadIdx.x;
  float c = counts[k];
  float t1 = 0.99f * cs_in[k];
  float t2 = 0.01f * c;
  float nc = t1 + t2;
  bool dead = nc < 0.5f;

  uint32_t bits;
#if THREEFRY_PARTITIONABLE
  {
    uint32_t o0, o1;
    threefry2x32(0u, 42u, 0u, (uint32_t)k, &o0, &o1);
    bits = o0 ^ o1;
  }
#else
  {
    uint32_t o0, o1;
    if (k < 512) { threefry2x32(0u, 42u, (uint32_t)k, (uint32_t)(k + 512), &o0, &o1); bits = o0; }
    else         { threefry2x32(0u, 42u, (uint32_t)(k - 512), (uint32_t)k, &o0, &o1); bits = o1; }
  }
#endif
  int r = (int)(bits & 0x7FFFu);

  float rep = dead ? 0.5f : nc;

  __shared__ float red[1024];
  red[k] = rep;
  __syncthreads();
  for (int s = 512; s > 0; s >>= 1) {
    if (k < s) red[k] += red[k + s];
    __syncthreads();
  }
  float n = red[0];

  float sm = ((rep + 1e-5f) / (n + 0.01024f)) * n;
  smooth[k] = sm;
  ridx[k] = r;
  deadf[k] = dead ? 1 : 0;
}

// Kernel 3: new embedding = (EMA avg or restart vec) / smoothed
__global__ __launch_bounds__(256) void k_emb(const float* __restrict__ wsum,
                                             const float* __restrict__ avg_in,
                                             const float* __restrict__ Z,
                                             const float* __restrict__ smooth,
                                             const int* __restrict__ ridx,
                                             const int* __restrict__ deadf,
                                             float* __restrict__ nemb) {
  int kd = blockIdx.x * 256 + threadIdx.x;
  int k = kd >> 7;
  int d = kd & (DD - 1);
  float t1 = 0.99f * avg_in[kd];
  float t2 = 0.01f * wsum[kd];
  float na = t1 + t2;
  if (deadf[k]) {
    int r = ridx[k];
    float zv = Z[((size_t)(r >> 12) * DD + d) * LL + (r & (LL - 1))];
    na = zv * 0.5f;
  }
  nemb[kd] = na / smooth[k];
}

// Kernel 4: tile-structured gather/output. Block = 32 rows (one b, l-tile).
// nemb rows fetched COALESCED (half-wave x float4 = 512B/row); Z via LDS transpose.
__global__ __launch_bounds__(256) void k_out(const float* __restrict__ Z,
                                             const float* __restrict__ nemb,
                                             const int* __restrict__ idxs,
                                             float* __restrict__ out,
                                             double* __restrict__ lacc) {
  __shared__ float Zt[128][33];   // [d][row]
  __shared__ float Ot[128][33];   // [d][row] output staged
  __shared__ int sidx[32];
  __shared__ float lred[4];

  const int tid = threadIdx.x;
  const int r0 = blockIdx.x * 32;
  const int b = r0 >> 12;
  const int l0 = r0 & (LL - 1);

  // stage Z tile coalesced (128B contiguous per d)
  const float* zsrc = Z + (size_t)b * DD * LL + l0;
#pragma unroll
  for (int p = 0; p < 4; ++p) {
    int f = p * 256 + tid;
    int d = f >> 3;
    int g = f & 7;
    float4 v = *(const float4*)(zsrc + (size_t)d * LL + g * 4);
    Zt[d][g * 4 + 0] = v.x;
    Zt[d][g * 4 + 1] = v.y;
    Zt[d][g * 4 + 2] = v.z;
    Zt[d][g * 4 + 3] = v.w;
  }
  if (tid < 32) sidx[tid] = idxs[r0 + tid];
  __syncthreads();

  // each 32-lane group handles one row per iter: coalesced 512B nemb row reads
  const int grp = tid >> 5;   // 0..7
  const int ln = tid & 31;
  float lsum = 0.0f;
#pragma unroll
  for (int it = 0; it < 4; ++it) {
    int row = it * 8 + grp;
    int fi = sidx[row];
    float4 q4 = *(const float4*)(nemb + (size_t)fi * DD + ln * 4);
    float z0 = Zt[ln * 4 + 0][row];
    float z1 = Zt[ln * 4 + 1][row];
    float z2 = Zt[ln * 4 + 2][row];
    float z3 = Zt[ln * 4 + 3][row];
    float o0 = z0 + (q4.x - z0);   // reference expr tree: z_e + (z_q - z_e)
    float o1 = z1 + (q4.y - z1);
    float o2 = z2 + (q4.z - z2);
    float o3 = z3 + (q4.w - z3);
    Ot[ln * 4 + 0][row] = o0;
    Ot[ln * 4 + 1][row] = o1;
    Ot[ln * 4 + 2][row] = o2;
    Ot[ln * 4 + 3][row] = o3;
    float d0 = z0 - q4.x, d1 = z1 - q4.y, d2 = z2 - q4.z, d3 = z3 - q4.w;
    lsum += d0 * d0 + d1 * d1 + d2 * d2 + d3 * d3;
  }
  __syncthreads();

  // write z_q_st coalesced (128B contiguous per d)
  float* dstz = out + (size_t)b * DD * LL + l0;
#pragma unroll
  for (int p = 0; p < 4; ++p) {
    int f = p * 256 + tid;
    int d = f >> 3;
    int g = f & 7;
    float4 v;
    v.x = Ot[d][g * 4 + 0];
    v.y = Ot[d][g * 4 + 1];
    v.z = Ot[d][g * 4 + 2];
    v.w = Ot[d][g * 4 + 3];
    *(float4*)(dstz + (size_t)d * LL + g * 4) = v;
  }
  // indices_map as floats
  if (tid < 32) out[(size_t)ZTOT + r0 + tid] = (float)sidx[tid];

  // loss partial: wave reduce then one double atomic per block
  for (int off = 32; off > 0; off >>= 1) lsum += __shfl_down(lsum, off, 64);
  if ((tid & 63) == 0) lred[tid >> 6] = lsum;
  __syncthreads();
  if (tid == 0) {
    float tot = (lred[0] + lred[1]) + (lred[2] + lred[3]);
    atomicAdd(lacc, (double)tot);
  }
}

// Kernel 5: final loss scalars
__global__ void k_fin(const double* __restrict__ lacc, float* __restrict__ out) {
  double S = lacc[0];
  float cb = (float)(S / (double)ZTOT);
  float bc = 0.25f * cb;
  float vq = cb + bc;
  float* o = out + (size_t)ZTOT + NN;
  o[0] = vq;
  o[1] = cb;
  o[2] = bc;
}

extern "C" void kernel_launch(void* const* d_in, const int* in_sizes, int n_in,
                              void* d_out, int out_size, void* d_ws, size_t ws_size,
                              hipStream_t stream) {
  const float* Z  = (const float*)d_in[0];   // z_e        (8,128,4096)
  const float* E  = (const float*)d_in[1];   // embedding  (1024,128)
  const float* CS = (const float*)d_in[2];   // cluster_size (1024,)
  const float* EA = (const float*)d_in[3];   // embedding_avg (1024,128)
  float* out = (float*)d_out;
  float* ws = (float*)d_ws;

  float* counts = ws;                        // 1024
  float* esq    = ws + 1024;                 // 1024
  float* smooth = ws + 2048;                 // 1024
  int*   ridx   = (int*)(ws + 3072);         // 1024
  int*   deadf  = (int*)(ws + 4096);         // 1024
  float* wsum   = ws + 8192;                 // 131072
  float* nemb   = ws + 8192 + 131072;        // 131072 floats (512 KB)
  int*   idxs   = (int*)(ws + 270336);       // 32768
  double* lacc  = (double*)(ws + 303104);    // 8B aligned

  // bf16-split E fragment buffers (256 KB each) reuse the nemb slot:
  // consumed by k_dist, overwritten later by k_emb (stream-ordered).
  ushort* E0f = (ushort*)nemb;
  ushort* E1f = (ushort*)(nemb + 65536);

  // zflat (N,D) = 16.8 MB parked in d_out[0..ZTOT): written by k_dist (fused
  // transpose), consumed by k_wsum, overwritten by k_out (stream-ordered).
  float* zflat = out;

  k_prep<<<KC, DD, 0, stream>>>(E, esq, lacc, E0f, E1f);
  k_dist<<<NN / 32, 256, 0, stream>>>(Z, E, E0f, E1f, esq, idxs, zflat);
  k_wsum<<<KC, 256, 0, stream>>>(zflat, idxs, wsum, counts);
  k_cluster<<<1, KC, 0, stream>>>(counts, CS, smooth, ridx, deadf);
  k_emb<<<(KC * DD) / 256, 256, 0, stream>>>(wsum, EA, Z, smooth, ridx, deadf, nemb);
  k_out<<<NN / 32, 256, 0, stream>>>(Z, nemb, idxs, out, lacc);
  k_fin<<<1, 1, 0, stream>>>(lacc, out);
}

// Round 12
// 109.101 us; speedup vs baseline: 3.9818x; 1.0841x over previous
//
#include <hip/hip_runtime.h>
#include <stdint.h>

// Problem constants (fixed by the reference)
constexpr int BB = 8;
constexpr int LL = 4096;
constexpr int DD = 128;
constexpr int KC = 1024;
constexpr int NN = BB * LL;          // 32768
constexpr int ZTOT = BB * DD * LL;   // 4194304

#define THREEFRY_PARTITIONABLE 1

typedef float f32x16 __attribute__((ext_vector_type(16)));
typedef short s16x8 __attribute__((ext_vector_type(8)));

union F4S8 { float4 f; s16x8 s; };

__device__ __forceinline__ ushort f2bf(float x) {   // RNE float->bf16
  uint32_t u = __float_as_uint(x);
  uint32_t r = u + 0x7FFFu + ((u >> 16) & 1u);
  return (ushort)(r >> 16);
}
__device__ __forceinline__ float bf2f(ushort h) {
  return __uint_as_float(((uint32_t)h) << 16);
}

__device__ __forceinline__ uint32_t rotl32(uint32_t x, int r) {
  return (x << r) | (x >> (32 - r));
}

__device__ __forceinline__ void threefry2x32(uint32_t k0, uint32_t k1,
                                             uint32_t x0, uint32_t x1,
                                             uint32_t* o0, uint32_t* o1) {
  uint32_t ks0 = k0, ks1 = k1, ks2 = 0x1BD11BDAu ^ k0 ^ k1;
  x0 += ks0; x1 += ks1;
  x0 += x1; x1 = rotl32(x1, 13); x1 ^= x0;
  x0 += x1; x1 = rotl32(x1, 15); x1 ^= x0;
  x0 += x1; x1 = rotl32(x1, 26); x1 ^= x0;
  x0 += x1; x1 = rotl32(x1, 6);  x1 ^= x0;
  x0 += ks1; x1 += ks2 + 1u;
  x0 += x1; x1 = rotl32(x1, 17); x1 ^= x0;
  x0 += x1; x1 = rotl32(x1, 29); x1 ^= x0;
  x0 += x1; x1 = rotl32(x1, 16); x1 ^= x0;
  x0 += x1; x1 = rotl32(x1, 24); x1 ^= x0;
  x0 += ks2; x1 += ks0 + 2u;
  x0 += x1; x1 = rotl32(x1, 13); x1 ^= x0;
  x0 += x1; x1 = rotl32(x1, 15); x1 ^= x0;
  x0 += x1; x1 = rotl32(x1, 26); x1 ^= x0;
  x0 += x1; x1 = rotl32(x1, 6);  x1 ^= x0;
  x0 += ks0; x1 += ks1 + 3u;
  x0 += x1; x1 = rotl32(x1, 17); x1 ^= x0;
  x0 += x1; x1 = rotl32(x1, 29); x1 ^= x0;
  x0 += x1; x1 = rotl32(x1, 16); x1 ^= x0;
  x0 += x1; x1 = rotl32(x1, 24); x1 ^= x0;
  x0 += ks1; x1 += ks2 + 4u;
  x0 += x1; x1 = rotl32(x1, 13); x1 ^= x0;
  x0 += x1; x1 = rotl32(x1, 15); x1 ^= x0;
  x0 += x1; x1 = rotl32(x1, 26); x1 ^= x0;
  x0 += x1; x1 = rotl32(x1, 6);  x1 ^= x0;
  x0 += ks2; x1 += ks0 + 5u;
  *o0 = x0; *o1 = x1;
}

// Kernel 0: e_sq per code, bf16-split E fragments (MFMA A-layout linear), lacc init.
// Frag layout: slot = ((k>>5)*8 + ks)*64 + (k&31) + 32*h ; 8 bf16 = dims ks*16+h*8+j.
__global__ __launch_bounds__(128) void k_prep(const float* __restrict__ E,
                                              float* __restrict__ esq,
                                              double* __restrict__ lacc,
                                              ushort* __restrict__ E0f,
                                              ushort* __restrict__ E1f) {
  const int k = blockIdx.x;       // code
  const int d = threadIdx.x;      // dim
  float v = E[k * DD + d];
  __shared__ float r[128];
  __shared__ ushort sh0[128], sh1[128];
  ushort h0 = f2bf(v);
  float v0 = bf2f(h0);
  ushort h1 = f2bf(v - v0);
  sh0[d] = h0; sh1[d] = h1;
  r[d] = v * v;
  __syncthreads();
  for (int s = 64; s > 0; s >>= 1) {
    if (d < s) r[d] += r[d + s];
    __syncthreads();
  }
  if (d == 0) {
    esq[k] = r[0];
    if (k == 0) lacc[0] = 0.0;
  }
  if (d < 32) {
    const ushort* src = (d < 16) ? sh0 : sh1;
    ushort* dst = (d < 16) ? E0f : E1f;
    int p = d & 15, h = p & 1, ks = p >> 1;
    int slot = ((k >> 5) * 8 + ks) * 64 + (k & 31) + 32 * h;
    int off = ks * 16 + h * 8;
    uint32_t w0 = (uint32_t)src[off + 0] | ((uint32_t)src[off + 1] << 16);
    uint32_t w1 = (uint32_t)src[off + 2] | ((uint32_t)src[off + 3] << 16);
    uint32_t w2 = (uint32_t)src[off + 4] | ((uint32_t)src[off + 5] << 16);
    uint32_t w3 = (uint32_t)src[off + 6] | ((uint32_t)src[off + 7] << 16);
    uint4 val; val.x = w0; val.y = w1; val.z = w2; val.w = w3;
    *(uint4*)(dst + (size_t)slot * 8) = val;
  }
}

// Kernel 1: MFMA distance argmin, 4-way code-split across waves for occupancy.
// Block: 256 thr = 4 waves; 32 rows/block; wave w scans codes [w*256,(w+1)*256).
// Also emits zflat (N,D) transposed rows (fused).
__global__ __launch_bounds__(256, 4) void k_dist(const float* __restrict__ Z,
                                                 const float* __restrict__ E,
                                                 const ushort* __restrict__ E0f,
                                                 const ushort* __restrict__ E1f,
                                                 const float* __restrict__ esq,
                                                 int* __restrict__ idx_out,
                                                 float* __restrict__ zflat) {
  __shared__ float Zt[128][33];    // [dim][row], pad 33: frag reads conflict-free
  __shared__ float esh[1024];      // 4 KB
  __shared__ float mv1[4][32], mv2[4][32];
  __shared__ int   mi1[4][32], mi2[4][32];

  const int tid = threadIdx.x;
  const int w = tid >> 6;          // wave id = code-split id
  const int lane = tid & 63;
  const int hi = lane >> 5;
  const int rr = lane & 31;
  const int r0 = blockIdx.x * 32;
  const int b = r0 >> 12;
  const int l0 = r0 & (LL - 1);

  // stage Z tile (32 rows): per dim, 128B contiguous
  const float* zsrc = Z + (size_t)b * DD * LL + l0;
#pragma unroll
  for (int p = 0; p < 4; ++p) {
    int f = p * 256 + tid;
    int d = f >> 3;
    int g = f & 7;
    float4 v = *(const float4*)(zsrc + (size_t)d * LL + g * 4);
    Zt[d][g * 4 + 0] = v.x;
    Zt[d][g * 4 + 1] = v.y;
    Zt[d][g * 4 + 2] = v.z;
    Zt[d][g * 4 + 3] = v.w;
  }
  {  // stage esq
    float4 e4 = *(const float4*)(esq + tid * 4);
    *(float4*)(&esh[tid * 4]) = e4;
  }
  __syncthreads();

  // fused zflat write: rows r0..r0+31 in (N,D) row-major
  {
    float* dst = zflat + (size_t)r0 * DD;
#pragma unroll
    for (int p = 0; p < 4; ++p) {
      int f = p * 256 + tid;
      int row = f >> 5;
      int dq = f & 31;
      float4 v;
      v.x = Zt[dq * 4 + 0][row];
      v.y = Zt[dq * 4 + 1][row];
      v.z = Zt[dq * 4 + 2][row];
      v.w = Zt[dq * 4 + 3][row];
      *(float4*)(dst + (size_t)row * DD + dq * 4) = v;
    }
  }

  // build B-frags (z bf16 splits): lane holds row rr, dims ks*16+hi*8+j
  s16x8 B0[8], B1[8];
#pragma unroll
  for (int ks = 0; ks < 8; ++ks) {
    s16x8 b0, b1;
#pragma unroll
    for (int j = 0; j < 8; ++j) {
      float z = Zt[ks * 16 + hi * 8 + j][rr];
      ushort h0 = f2bf(z);
      float z0f = bf2f(h0);
      ushort h1 = f2bf(z - z0f);
      b0[j] = (short)h0;
      b1[j] = (short)h1;
    }
    B0[ks] = b0; B1[ks] = b1;
  }

  // wave scans its 8 code-subtiles (codes w*256 .. w*256+255, ascending)
  float b1v = 3.4e38f, b2v = 3.4e38f;
  int b1i = 0, b2i = 0;
  const float4* e0p = (const float4*)E0f;
  const float4* e1p = (const float4*)E1f;

  for (int s = 0; s < 8; ++s) {
    const int sg = w * 8 + s;        // global subtile
    f32x16 acc;
#pragma unroll
    for (int i = 0; i < 16; ++i) acc[i] = 0.0f;
    const int base = sg * 512 + lane;
#pragma unroll
    for (int ks = 0; ks < 8; ++ks) {
      F4S8 ua, ub;
      ua.f = e0p[base + ks * 64];
      ub.f = e1p[base + ks * 64];
      acc = __builtin_amdgcn_mfma_f32_32x32x16_bf16(ua.s, B0[ks], acc, 0, 0, 0);
      acc = __builtin_amdgcn_mfma_f32_32x32x16_bf16(ua.s, B1[ks], acc, 0, 0, 0);
      acc = __builtin_amdgcn_mfma_f32_32x32x16_bf16(ub.s, B0[ks], acc, 0, 0, 0);
    }
    // finalize: lane-local codes, ascending -> first-index tie-break
#pragma unroll
    for (int reg = 0; reg < 16; ++reg) {
      int cl = (reg & 3) + 8 * (reg >> 2) + 4 * hi;
      int c = sg * 32 + cl;
      float rv = fmaf(-2.0f, acc[reg], esh[c]);   // zsq-free ranking key
      if (rv < b1v) { b2v = b1v; b2i = b1i; b1v = rv; b1i = c; }
      else if (rv < b2v) { b2v = rv; b2i = c; }
    }
  }

  // merge the two half-lanes (codes interleave -> lexicographic (val, idx))
  float ov1 = __shfl_xor(b1v, 32, 64); int oi1 = __shfl_xor(b1i, 32, 64);
  float ov2 = __shfl_xor(b2v, 32, 64); int oi2 = __shfl_xor(b2i, 32, 64);
  if (ov1 < b1v || (ov1 == b1v && oi1 < b1i)) { b2v = b1v; b2i = b1i; b1v = ov1; b1i = oi1; }
  else if (ov1 < b2v || (ov1 == b2v && oi1 < b2i)) { b2v = ov1; b2i = oi1; }
  if (ov2 < b2v || (ov2 == b2v && oi2 < b2i)) { b2v = ov2; b2i = oi2; }

  if (hi == 0) {
    mv1[w][rr] = b1v; mi1[w][rr] = b1i;
    mv2[w][rr] = b2v; mi2[w][rr] = b2i;
  }
  __syncthreads();

  // final merge across 4 waves + selective exact refine, one thread per row
  if (tid < 32) {
    const int row = tid;
    float fb1 = mv1[0][row]; int fi1 = mi1[0][row];
    float fb2 = mv2[0][row]; int fi2 = mi2[0][row];
#pragma unroll
    for (int q = 1; q < 4; ++q) {
      float v1 = mv1[q][row]; int i1 = mi1[q][row];
      float v2 = mv2[q][row]; int i2 = mi2[q][row];
      if (v1 < fb1 || (v1 == fb1 && i1 < fi1)) {
        fb2 = fb1; fi2 = fi1; fb1 = v1; fi1 = i1;
      } else if (v1 < fb2 || (v1 == fb2 && i1 < fi2)) {
        fb2 = v1; fi2 = i1;
      }
      if (v2 < fb2 || (v2 == fb2 && i2 < fi2)) { fb2 = v2; fi2 = i2; }
    }

    int fi = fi1;
    if (fb2 - fb1 <= 4e-5f) {
      float zsq = 0.0f;
#pragma unroll 4
      for (int d = 0; d < 128; ++d) {
        float z = Zt[d][row];
        zsq = fmaf(z, z, zsq);
      }
      float dot1 = 0.0f, dot2 = 0.0f;
      const float* e1r = E + (size_t)fi1 * DD;
      const float* e2r = E + (size_t)fi2 * DD;
      for (int d = 0; d < 128; ++d) {
        float z = Zt[d][row];
        dot1 = fmaf(z, e1r[d], dot1);
        dot2 = fmaf(z, e2r[d], dot2);
      }
      float k1 = (zsq + esh[fi1]) - 2.0f * dot1;
      float k2 = (zsq + esh[fi2]) - 2.0f * dot2;
      if (k2 < k1 || (k2 == k1 && fi2 < fi1)) fi = fi2;
    }
    idx_out[r0 + row] = fi;
  }
}

// Counting-sort phase 1: per-block histogram of 1024 indices.
__global__ __launch_bounds__(1024) void k_hist(const int* __restrict__ idxs,
                                               int* __restrict__ part_cnt) {
  __shared__ int h[1024];
  const int tid = threadIdx.x;
  const int j = blockIdx.x;      // 32 blocks
  h[tid] = 0;
  __syncthreads();
  int k = idxs[j * 1024 + tid];
  atomicAdd(&h[k], 1);
  __syncthreads();
  part_cnt[j * 1024 + tid] = h[tid];
}

// Counting-sort phase 2: column prefix over 32 blocks + exclusive prefix over
// codes. Emits part_base (in-place), code_start, int & float counts.
__global__ __launch_bounds__(1024) void k_scan(int* __restrict__ part_cnt,
                                               int* __restrict__ code_start,
                                               int* __restrict__ icnt,
                                               float* __restrict__ counts) {
  const int k = threadIdx.x;
  int base[32];
  int s = 0;
#pragma unroll
  for (int j = 0; j < 32; ++j) {
    base[j] = s;
    s += part_cnt[j * 1024 + k];
  }
  icnt[k] = s;
  counts[k] = (float)s;

  __shared__ int ps[1024];
  ps[k] = s;
  __syncthreads();
  for (int off = 1; off < 1024; off <<= 1) {
    int v = (k >= off) ? ps[k - off] : 0;
    __syncthreads();
    ps[k] += v;
    __syncthreads();
  }
  int excl = ps[k] - s;
  code_start[k] = excl;
#pragma unroll
  for (int j = 0; j < 32; ++j) {
    part_cnt[j * 1024 + k] = excl + base[j];   // becomes part_base
  }
}

// Counting-sort phase 3: scatter row ids into code-grouped rowlist.
__global__ __launch_bounds__(1024) void k_scatter(const int* __restrict__ idxs,
                                                  const int* __restrict__ part_base,
                                                  int* __restrict__ rowlist) {
  __shared__ int cur[1024];
  const int tid = threadIdx.x;
  const int j = blockIdx.x;      // 32 blocks
  cur[tid] = part_base[j * 1024 + tid];
  __syncthreads();
  int row = j * 1024 + tid;
  int k = idxs[row];
  int pos = atomicAdd(&cur[k], 1);
  rowlist[pos] = row;
}

// Kernel B2: scan-free gather segment sum via rowlist.
__global__ __launch_bounds__(256) void k_wsum2(const float* __restrict__ zflat,
                                               const int* __restrict__ rowlist,
                                               const int* __restrict__ code_start,
                                               const int* __restrict__ icnt,
                                               float* __restrict__ wsum) {
  const int k = blockIdx.x;
  const int tid = threadIdx.x;
  const int h = tid >> 7;        // 0/1
  const int d = tid & 127;
  __shared__ float red[128];

  const int start = code_start[k];
  const int m = icnt[k];
  float acc = 0.0f;
  for (int j = h; j < m; j += 2) {
    int row = rowlist[start + j];
    acc += zflat[(size_t)row * DD + d];
  }
  if (h == 1) red[d] = acc;
  __syncthreads();
  if (h == 0) {
    wsum[k * DD + d] = acc + red[d];
  }
}

// Kernel 2: cluster-size EMA, dead detection, threefry restart indices, smoothing
__global__ __launch_bounds__(1024) void k_cluster(const float* __restrict__ counts,
                                                  const float* __restrict__ cs_in,
                                                  float* __restrict__ smooth,
                                                  int* __restrict__ ridx,
                                                  int* __restrict__ deadf) {
  const int k = threadIdx.x;
  float c = counts[k];
  float t1 = 0.99f * cs_in[k];
  float t2 = 0.01f * c;
  float nc = t1 + t2;
  bool dead = nc < 0.5f;

  uint32_t bits;
#if THREEFRY_PARTITIONABLE
  {
    uint32_t o0, o1;
    threefry2x32(0u, 42u, 0u, (uint32_t)k, &o0, &o1);
    bits = o0 ^ o1;
  }
#else
  {
    uint32_t o0, o1;
    if (k < 512) { threefry2x32(0u, 42u, (uint32_t)k, (uint32_t)(k + 512), &o0, &o1); bits = o0; }
    else         { threefry2x32(0u, 42u, (uint32_t)(k - 512), (uint32_t)k, &o0, &o1); bits = o1; }
  }
#endif
  int r = (int)(bits & 0x7FFFu);

  float rep = dead ? 0.5f : nc;

  __shared__ float red[1024];
  red[k] = rep;
  __syncthreads();
  for (int s = 512; s > 0; s >>= 1) {
    if (k < s) red[k] += red[k + s];
    __syncthreads();
  }
  float n = red[0];

  float sm = ((rep + 1e-5f) / (n + 0.01024f)) * n;
  smooth[k] = sm;
  ridx[k] = r;
  deadf[k] = dead ? 1 : 0;
}

// Kernel 3: new embedding = (EMA avg or restart vec) / smoothed
__global__ __launch_bounds__(256) void k_emb(const float* __restrict__ wsum,
                                             const float* __restrict__ avg_in,
                                             const float* __restrict__ Z,
                                             const float* __restrict__ smooth,
                                             const int* __restrict__ ridx,
                                             const int* __restrict__ deadf,
                                             float* __restrict__ nemb) {
  int kd = blockIdx.x * 256 + threadIdx.x;
  int k = kd >> 7;
  int d = kd & (DD - 1);
  float t1 = 0.99f * avg_in[kd];
  float t2 = 0.01f * wsum[kd];
  float na = t1 + t2;
  if (deadf[k]) {
    int r = ridx[k];
    float zv = Z[((size_t)(r >> 12) * DD + d) * LL + (r & (LL - 1))];
    na = zv * 0.5f;
  }
  nemb[kd] = na / smooth[k];
}

// Kernel 4: tile-structured gather/output. Block = 32 rows (one b, l-tile).
// nemb rows fetched COALESCED (half-wave x float4 = 512B/row); Z via LDS transpose.
__global__ __launch_bounds__(256) void k_out(const float* __restrict__ Z,
                                             const float* __restrict__ nemb,
                                             const int* __restrict__ idxs,
                                             float* __restrict__ out,
                                             double* __restrict__ lacc) {
  __shared__ float Zt[128][33];   // [d][row]
  __shared__ float Ot[128][33];   // [d][row] output staged
  __shared__ int sidx[32];
  __shared__ float lred[4];

  const int tid = threadIdx.x;
  const int r0 = blockIdx.x * 32;
  const int b = r0 >> 12;
  const int l0 = r0 & (LL - 1);

  // stage Z tile coalesced (128B contiguous per d)
  const float* zsrc = Z + (size_t)b * DD * LL + l0;
#pragma unroll
  for (int p = 0; p < 4; ++p) {
    int f = p * 256 + tid;
    int d = f >> 3;
    int g = f & 7;
    float4 v = *(const float4*)(zsrc + (size_t)d * LL + g * 4);
    Zt[d][g * 4 + 0] = v.x;
    Zt[d][g * 4 + 1] = v.y;
    Zt[d][g * 4 + 2] = v.z;
    Zt[d][g * 4 + 3] = v.w;
  }
  if (tid < 32) sidx[tid] = idxs[r0 + tid];
  __syncthreads();

  // each 32-lane group handles one row per iter: coalesced 512B nemb row reads
  const int grp = tid >> 5;   // 0..7
  const int ln = tid & 31;
  float lsum = 0.0f;
#pragma unroll
  for (int it = 0; it < 4; ++it) {
    int row = it * 8 + grp;
    int fi = sidx[row];
    float4 q4 = *(const float4*)(nemb + (size_t)fi * DD + ln * 4);
    float z0 = Zt[ln * 4 + 0][row];
    float z1 = Zt[ln * 4 + 1][row];
    float z2 = Zt[ln * 4 + 2][row];
    float z3 = Zt[ln * 4 + 3][row];
    float o0 = z0 + (q4.x - z0);   // reference expr tree: z_e + (z_q - z_e)
    float o1 = z1 + (q4.y - z1);
    float o2 = z2 + (q4.z - z2);
    float o3 = z3 + (q4.w - z3);
    Ot[ln * 4 + 0][row] = o0;
    Ot[ln * 4 + 1][row] = o1;
    Ot[ln * 4 + 2][row] = o2;
    Ot[ln * 4 + 3][row] = o3;
    float d0 = z0 - q4.x, d1 = z1 - q4.y, d2 = z2 - q4.z, d3 = z3 - q4.w;
    lsum += d0 * d0 + d1 * d1 + d2 * d2 + d3 * d3;
  }
  __syncthreads();

  // write z_q_st coalesced (128B contiguous per d)
  float* dstz = out + (size_t)b * DD * LL + l0;
#pragma unroll
  for (int p = 0; p < 4; ++p) {
    int f = p * 256 + tid;
    int d = f >> 3;
    int g = f & 7;
    float4 v;
    v.x = Ot[d][g * 4 + 0];
    v.y = Ot[d][g * 4 + 1];
    v.z = Ot[d][g * 4 + 2];
    v.w = Ot[d][g * 4 + 3];
    *(float4*)(dstz + (size_t)d * LL + g * 4) = v;
  }
  // indices_map as floats
  if (tid < 32) out[(size_t)ZTOT + r0 + tid] = (float)sidx[tid];

  // loss partial: wave reduce then one double atomic per block
  for (int off = 32; off > 0; off >>= 1) lsum += __shfl_down(lsum, off, 64);
  if ((tid & 63) == 0) lred[tid >> 6] = lsum;
  __syncthreads();
  if (tid == 0) {
    float tot = (lred[0] + lred[1]) + (lred[2] + lred[3]);
    atomicAdd(lacc, (double)tot);
  }
}

// Kernel 5: final loss scalars
__global__ void k_fin(const double* __restrict__ lacc, float* __restrict__ out) {
  double S = lacc[0];
  float cb = (float)(S / (double)ZTOT);
  float bc = 0.25f * cb;
  float vq = cb + bc;
  float* o = out + (size_t)ZTOT + NN;
  o[0] = vq;
  o[1] = cb;
  o[2] = bc;
}

extern "C" void kernel_launch(void* const* d_in, const int* in_sizes, int n_in,
                              void* d_out, int out_size, void* d_ws, size_t ws_size,
                              hipStream_t stream) {
  const float* Z  = (const float*)d_in[0];   // z_e        (8,128,4096)
  const float* E  = (const float*)d_in[1];   // embedding  (1024,128)
  const float* CS = (const float*)d_in[2];   // cluster_size (1024,)
  const float* EA = (const float*)d_in[3];   // embedding_avg (1024,128)
  float* out = (float*)d_out;
  float* ws = (float*)d_ws;

  float* counts = ws;                        // 1024
  float* esq    = ws + 1024;                 // 1024
  float* smooth = ws + 2048;                 // 1024
  int*   ridx   = (int*)(ws + 3072);         // 1024
  int*   deadf  = (int*)(ws + 4096);         // 1024
  float* wsum   = ws + 8192;                 // 131072
  float* nemb   = ws + 8192 + 131072;        // 131072 floats (512 KB)
  int*   idxs   = (int*)(ws + 270336);       // 32768
  double* lacc  = (double*)(ws + 303104);    // 8B aligned (ends 303108)

  // new sort buffers (fresh ws past lacc)
  int* rowlist    = (int*)(ws + 303360);     // 32768 ints  -> ends 336128
  int* code_start = (int*)(ws + 336128);     // 1024 ints
  int* icnt       = (int*)(ws + 337152);     // 1024 ints   -> ends 338176

  // bf16-split E fragment buffers (256 KB each) reuse the nemb slot:
  // consumed by k_dist; part_cnt then reuses the same slot (E-frags dead);
  // k_emb finally overwrites nemb (stream-ordered).
  ushort* E0f = (ushort*)nemb;
  ushort* E1f = (ushort*)(nemb + 65536);
  int* part_cnt = (int*)nemb;                // 32*1024 ints = 512 KB exactly

  // zflat (N,D) = 16.8 MB parked in d_out[0..ZTOT): written by k_dist (fused
  // transpose), consumed by k_wsum2, overwritten by k_out (stream-ordered).
  float* zflat = out;

  k_prep<<<KC, DD, 0, stream>>>(E, esq, lacc, E0f, E1f);
  k_dist<<<NN / 32, 256, 0, stream>>>(Z, E, E0f, E1f, esq, idxs, zflat);
  k_hist<<<32, 1024, 0, stream>>>(idxs, part_cnt);
  k_scan<<<1, 1024, 0, stream>>>(part_cnt, code_start, icnt, counts);
  k_scatter<<<32, 1024, 0, stream>>>(idxs, part_cnt, rowlist);
  k_wsum2<<<KC, 256, 0, stream>>>(zflat, rowlist, code_start, icnt, wsum);
  k_cluster<<<1, KC, 0, stream>>>(counts, CS, smooth, ridx, deadf);
  k_emb<<<(KC * DD) / 256, 256, 0, stream>>>(wsum, EA, Z, smooth, ridx, deadf, nemb);
  k_out<<<NN / 32, 256, 0, stream>>>(Z, nemb, idxs, out, lacc);
  k_fin<<<1, 1, 0, stream>>>(lacc, out);
}